// Round 11
// baseline (448.686 us; speedup 1.0000x reference)
//
#include <hip/hip_runtime.h>
#include <hip/hip_bf16.h>
#include <math.h>

typedef __hip_bfloat16 bf16;
typedef __attribute__((ext_vector_type(8))) __bf16 bf16x8;
typedef __attribute__((ext_vector_type(8))) unsigned short u16x8;
typedef __attribute__((ext_vector_type(4))) float f32x4;

#define H_ 300
#define W_ 300
#define HW_ 90000
#define NBATCH 32
#define NPART (NBATCH * 190)   // gated BN partials: one per gated (image,tile)
#define NPB 95                 // partial rows per reduce_parts block (6080/64)

__device__ __forceinline__ float b2f(unsigned short u) {
    return __uint_as_float((unsigned int)u << 16);
}
__device__ __forceinline__ unsigned short f2u(float v) {
    bf16 b = __float2bfloat16(v);
    return *reinterpret_cast<unsigned short*>(&b);
}
__device__ __forceinline__ float sigm(float x) { return 1.f / (1.f + __expf(-x)); }
// HW packed fp32->bf16 pair (RNE), 1 instr vs ~10 for the manual sequence.
__device__ __forceinline__ unsigned int packbf(float a, float b) {
    unsigned int r;
    asm("v_cvt_pk_bf16_f32 %0, %1, %2" : "=v"(r) : "v"(a), "v"(b));
    return r;
}

// ---------------------------------------------------------------------------
// All weight prepacks in ONE launch (7 blocks). Fragment order: A operand,
// row = lane&15 = co, k = (lane>>4)*8+j; pack[step][g][lane][j] bf16.
// Block 4 is the convc composite (see convc3_k).
// ---------------------------------------------------------------------------
__global__ void pack_all_k(
    const float* __restrict__ w1, const float* __restrict__ w2,
    const float* __restrict__ w3, const float* __restrict__ w4,
    const float* __restrict__ w5, const float* __restrict__ wc5,
    const float* __restrict__ wc10, const float* __restrict__ wc15,
    const float* __restrict__ wg, const float* __restrict__ wm,
    unsigned short* __restrict__ WP)
{
    const float *a = nullptr, *bsec = nullptr;
    int cs = 999, CO = 0, CI = 0, CP = 8, NS = 3, NG = 1, off = 0, special = 0;
    switch (blockIdx.x) {
        case 0: a = w2;  CO = 16; CI = 8;  CP = 8;  NS = 3; off = 0;     break;
        case 1: a = w3;  CO = 32; CI = 16; CP = 16; NS = 5; NG = 2; off = 2048;  break;
        case 2: a = w4;  CO = 16; CI = 32; CP = 32; NS = 9; off = 8192;  break;
        case 3: a = w5;  CO = 8;  CI = 16; CP = 16; NS = 5; off = 13312; break;
        case 4: special = 1; CO = 32; CI = 32; CP = 32; NS = 9; NG = 2;
                off = 16384; break;
        case 5: a = wg; bsec = wm; cs = 8; CO = 16; CI = 24; CP = 32; NS = 9;
                off = 25600; break;
        case 6: a = w1;  CO = 8;  CI = 3;  CP = 8;  NS = 3; off = 30720; break;
    }
    unsigned short* outp = WP + off;
    int TPK = 32 / CP;
    int total = NS * NG * 512;
    for (int idx = threadIdx.x; idx < total; idx += 256) {
        int j = idx & 7;
        int lane = (idx >> 3) & 63;
        int g = (idx >> 9) % NG;
        int s = idx / (512 * NG);
        int col = lane & 15, kg = lane >> 4;
        int kk = kg * 8 + j;
        int tt = kk / CP, ci = kk % CP;
        int tap = s * TPK + tt;
        float v = 0.f;
        if (special) {
            int o = ci >> 3, c8 = ci & 7;
            int convid = (g == 0) ? (col < 8 ? 0 : 1) : (col < 8 ? 2 : -1);
            if (tap < 9 && convid >= 0) {
                const float* wc = (convid == 0) ? wc5 : (convid == 1) ? wc10 : wc15;
                int colc = col & 7;
                if (o == 0) v = wc[(colc * 16 + c8) * 9 + tap];
                else if (o == convid + 1) v = wc[(colc * 16 + 8 + c8) * 9 + tap];
            }
        } else {
            int co = g * 16 + col;
            if (tap < 9 && ci < CI && co < CO)
                v = (co >= cs) ? bsec[((co - cs) * CI + ci) * 9 + tap]
                               : a[(co * CI + ci) * 9 + tap];
        }
        outp[idx] = f2u(v);
    }
}

// ---------------------------------------------------------------------------
// MFMA implicit-GEMM 3x3 conv, NHWC in/out. Tile 32xTH px, 4 waves.
// Octet-planar LDS s_in[buf][oct][(TH+2)*34 px][8ch]. OCT==4 uses a
// ROW-CACHED inner loop (3 new ds_reads/row instead of 9).
// PIPE==1 (OCT4/TH16 only): block processes TWO images (z, z+zimgs) with
// double-buffered LDS; image 2's global loads are issued into registers
// BEFORE image 1's compute (T14 async-STAGE split) to hide HBM latency.
// MODE 0: plain. MODE 2: gated (rows 0-7 g, 8-15 m; out = g*sigm(m)) and
// fused BN partial stats (one float2x8 per (image,tile)). MODE 3: conv1.
// ---------------------------------------------------------------------------
template <int CIN, int CINP, int COUT, int NGI, int MODE, int TH, int PIPE>
__global__ __launch_bounds__(256) void mfconv_k(
    const unsigned short* __restrict__ src,
    const unsigned short* __restrict__ wpack,
    const float* __restrict__ bias0, const float* __restrict__ bias1,
    unsigned short* __restrict__ out, int co_total, int co_off,
    float2* __restrict__ bnp, int img_base, int zimgs)
{
    constexpr int TPK = 32 / CINP;
    constexpr int NSTEP = (9 + TPK - 1) / TPK;
    constexpr int OCT = CINP / 8;
    constexpr int NPX = (TH + 2) * 34;
    constexpr int NIMG = PIPE ? 2 : 1;
    static_assert(!PIPE || (OCT == 4 && TH == 16), "PIPE only for OCT4/TH16");

    __shared__ __align__(16) unsigned short s_in[(PIPE ? 2 : 1) * OCT * NPX * 8];

    int z = blockIdx.z;
    int x0 = blockIdx.x * 32, y0 = blockIdx.y * TH;
    int tid = threadIdx.x;
    int lane = tid & 63, wv = tid >> 6;
    bool interior = (x0 >= 1) && (x0 + 32 < W_) && (y0 >= 1) && (y0 + TH < H_);

    int oct = (OCT == 1) ? 0 : (wv % OCT);
    int phase = (OCT == 4) ? 0 : (wv / OCT);
    bool voct = (CIN == CINP) || (oct * 8 < CIN);

    // ---- direct stager (PIPE=0 path and initial stage fallback) ----
    auto stage_direct = [&](int b, unsigned short* sbuf) {
        if (MODE == 3) {
            const float* sf =
                reinterpret_cast<const float*>(src) + (size_t)b * 3 * HW_;
            if (interior) {
                const float* sf0 = sf + (size_t)(y0 - 1) * W_ + (x0 - 1);
                for (int e = tid; e < NPX; e += 256) {
                    int y = e / 34;
                    size_t o = (size_t)e + (size_t)y * 266;
                    u16x8 v = {0, 0, 0, 0, 0, 0, 0, 0};
                    v[0] = f2u(sf0[o]);
                    v[1] = f2u(sf0[HW_ + o]);
                    v[2] = f2u(sf0[2 * HW_ + o]);
                    *(u16x8*)&sbuf[e * 8] = v;
                }
            } else {
                for (int e = tid; e < NPX; e += 256) {
                    int y = e / 34, x = e - y * 34;
                    int gy = y0 + y - 1, gx = x0 + x - 1;
                    u16x8 v = {0, 0, 0, 0, 0, 0, 0, 0};
                    if (gy >= 0 && gy < H_ && gx >= 0 && gx < W_) {
                        size_t o = (size_t)gy * W_ + gx;
                        v[0] = f2u(sf[o]);
                        v[1] = f2u(sf[HW_ + o]);
                        v[2] = f2u(sf[2 * HW_ + o]);
                    }
                    *(u16x8*)&sbuf[e * 8] = v;
                }
            }
        } else {
            const unsigned short* sb = src + (size_t)b * CIN * HW_;
            if (interior) {
                const unsigned short* sb0 =
                    sb + ((size_t)(y0 - 1) * W_ + (x0 - 1)) * CIN + oct * 8;
                for (int px = lane + phase * 64; px < NPX; px += 256 / OCT) {
                    int y = px / 34;
                    u16x8 v;
                    if (voct)
                        v = *(const u16x8*)&sb0[(size_t)(px + y * 266) * CIN];
                    else
                        v = (u16x8){0, 0, 0, 0, 0, 0, 0, 0};
                    *(u16x8*)&sbuf[(oct * NPX + px) * 8] = v;
                }
            } else {
                for (int px = lane + phase * 64; px < NPX; px += 256 / OCT) {
                    int y = px / 34, x = px - y * 34;
                    int gy = y0 + y - 1, gx = x0 + x - 1;
                    u16x8 v = {0, 0, 0, 0, 0, 0, 0, 0};
                    if (gy >= 0 && gy < H_ && gx >= 0 && gx < W_ && voct)
                        v = *(const u16x8*)&sb[((size_t)gy * W_ + gx) * CIN +
                                               oct * 8];
                    *(u16x8*)&sbuf[(oct * NPX + px) * 8] = v;
                }
            }
        }
    };

    // ---- PIPE: register staging (load early, LDS-write late) ----
    u16x8 pre[PIPE ? 10 : 1];
    auto stage_load = [&](int b) {
        if constexpr (PIPE) {
            const unsigned short* sb = src + (size_t)b * CIN * HW_;
            if (interior) {
                const unsigned short* sb0 =
                    sb + ((size_t)(y0 - 1) * W_ + (x0 - 1)) * CIN + oct * 8;
#pragma unroll
                for (int k = 0; k < 10; ++k) {
                    int px = lane + k * 64;
                    u16x8 v = {0, 0, 0, 0, 0, 0, 0, 0};
                    if (px < NPX && voct) {
                        int y = px / 34;
                        v = *(const u16x8*)&sb0[(size_t)(px + y * 266) * CIN];
                    }
                    pre[k] = v;
                }
            } else {
#pragma unroll
                for (int k = 0; k < 10; ++k) {
                    int px = lane + k * 64;
                    u16x8 v = {0, 0, 0, 0, 0, 0, 0, 0};
                    if (px < NPX) {
                        int y = px / 34, x = px - y * 34;
                        int gy = y0 + y - 1, gx = x0 + x - 1;
                        if (gy >= 0 && gy < H_ && gx >= 0 && gx < W_ && voct)
                            v = *(const u16x8*)&sb[((size_t)gy * W_ + gx) * CIN +
                                                   oct * 8];
                    }
                    pre[k] = v;
                }
            }
        }
    };
    auto stage_write = [&](int bsel) {
        if constexpr (PIPE) {
            unsigned short* sbuf = s_in + (size_t)bsel * (OCT * NPX * 8);
#pragma unroll
            for (int k = 0; k < 10; ++k) {
                int px = lane + k * 64;
                if (px < NPX) *(u16x8*)&sbuf[(oct * NPX + px) * 8] = pre[k];
            }
        }
    };

    // ---- weight fragments / biases (image-independent) ----
    bf16x8 bw[NGI][NSTEP];
#pragma unroll
    for (int gi = 0; gi < NGI; ++gi)
#pragma unroll
        for (int s = 0; s < NSTEP; ++s)
            bw[gi][s] = *(const bf16x8*)&wpack[((s * NGI + gi) * 64 + lane) * 8];

    int col = lane & 15, kg = lane >> 4;

    float bias_r[NGI][4];
#pragma unroll
    for (int gi = 0; gi < NGI; ++gi)
#pragma unroll
        for (int r = 0; r < 4; ++r) {
            if (MODE == 2)
                bias_r[0][r] = (kg < 2) ? bias0[kg * 4 + r] : bias1[(kg - 2) * 4 + r];
            else {
                int co_l = gi * 16 + kg * 4 + r;
                bias_r[gi][r] = (co_l < COUT) ? bias0[co_l] : 0.f;
            }
        }

    // ---- initial stage ----
    if constexpr (PIPE) {
        stage_load(z);
        stage_write(0);
    } else {
        stage_direct(z, s_in);
    }
    __syncthreads();

#pragma unroll
    for (int i = 0; i < NIMG; ++i) {
        int b = z + i * zimgs;
        if (PIPE && i + 1 < NIMG) stage_load(z + (i + 1) * zimgs);
        unsigned short* sbuf =
            s_in + (PIPE ? (size_t)(i & 1) * (OCT * NPX * 8) : 0);

        float bs[4] = {0.f, 0.f, 0.f, 0.f}, bs2[4] = {0.f, 0.f, 0.f, 0.f};

        if constexpr (OCT == 4) {
            // ---- row-cached inner loop (TPK==1: step s == tap s) ----
            int myb = wv * (TH / 4);
#pragma unroll
            for (int tx = 0; tx < 2; ++tx) {
                int pbase = kg * NPX + tx * 16 + col;
                bf16x8 fr[3][3];
#pragma unroll
                for (int r = 0; r < 2; ++r)
#pragma unroll
                    for (int dx = 0; dx < 3; ++dx)
                        fr[r][dx] =
                            *(const bf16x8*)&sbuf[(pbase + (myb + r) * 34 + dx) * 8];
#pragma unroll
                for (int ii = 0; ii < TH / 4; ++ii) {
#pragma unroll
                    for (int dx = 0; dx < 3; ++dx)
                        fr[(ii + 2) % 3][dx] = *(const bf16x8*)&sbuf
                            [(pbase + (myb + ii + 2) * 34 + dx) * 8];

                    f32x4 acc[NGI];
#pragma unroll
                    for (int gi = 0; gi < NGI; ++gi) acc[gi] = {0.f, 0.f, 0.f, 0.f};
#pragma unroll
                    for (int dy = 0; dy < 3; ++dy)
#pragma unroll
                        for (int dx = 0; dx < 3; ++dx) {
                            bf16x8 a = fr[(ii + dy) % 3][dx];
#pragma unroll
                            for (int gi = 0; gi < NGI; ++gi)
                                acc[gi] = __builtin_amdgcn_mfma_f32_16x16x32_bf16(
                                    bw[gi][dy * 3 + dx], a, acc[gi], 0, 0, 0);
                        }

                    int gy = y0 + myb + ii;
                    int gxx = x0 + tx * 16 + col;
                    if (gy < H_) {
                        if (MODE == 2) {
                            float v0 = acc[0].x + bias_r[0][0];
                            float v1 = acc[0].y + bias_r[0][1];
                            float v2 = acc[0].z + bias_r[0][2];
                            float v3 = acc[0].w + bias_r[0][3];
                            float m0 = __shfl_xor(v0, 32), m1 = __shfl_xor(v1, 32);
                            float m2 = __shfl_xor(v2, 32), m3 = __shfl_xor(v3, 32);
                            if (kg < 2 && gxx < W_) {
                                float o0 = v0 * sigm(m0), o1 = v1 * sigm(m1);
                                float o2 = v2 * sigm(m2), o3 = v3 * sigm(m3);
                                uint2 st;
                                st.x = packbf(o0, o1);
                                st.y = packbf(o2, o3);
                                *(uint2*)&out[(((size_t)b * HW_ +
                                                (size_t)gy * W_ + gxx) * 8) +
                                              kg * 4] = st;
                                bs[0] += o0; bs2[0] += o0 * o0;
                                bs[1] += o1; bs2[1] += o1 * o1;
                                bs[2] += o2; bs2[2] += o2 * o2;
                                bs[3] += o3; bs2[3] += o3 * o3;
                            }
                        } else {
#pragma unroll
                            for (int gi = 0; gi < NGI; ++gi) {
                                int co_g = gi * 16 + kg * 4;
                                if (co_g < COUT && gxx < W_) {
                                    uint2 st;
                                    st.x = packbf(acc[gi].x + bias_r[gi][0],
                                                  acc[gi].y + bias_r[gi][1]);
                                    st.y = packbf(acc[gi].z + bias_r[gi][2],
                                                  acc[gi].w + bias_r[gi][3]);
                                    *(uint2*)&out[((size_t)b * HW_ +
                                                   (size_t)gy * W_ + gxx) *
                                                      co_total + co_off + co_g] = st;
                                }
                            }
                        }
                    }
                }
            }
        } else {
            // ---- generic loop for OCT<=2 ----
            int offs[NSTEP];
#pragma unroll
            for (int s = 0; s < NSTEP; ++s) {
                int t = s * TPK + kg / OCT;
                if (t > 8) t = 8;  // padded taps: weights are zero there
                offs[s] = ((t / 3) * 34 + (t % 3)) * 8 + (kg % OCT) * (NPX * 8);
            }

#pragma unroll
            for (int i2 = 0; i2 < TH / 2; ++i2) {
                int m = wv * (TH / 2) + i2;
                int my = m >> 1, tx = m & 1;
                int gy = y0 + my;
                if (gy >= H_) continue;  // wave-uniform
                int base = (my * 34 + tx * 16 + col) * 8;

                f32x4 acc[NGI];
#pragma unroll
                for (int gi = 0; gi < NGI; ++gi) acc[gi] = {0.f, 0.f, 0.f, 0.f};
#pragma unroll
                for (int s = 0; s < NSTEP; ++s) {
                    bf16x8 a = *(const bf16x8*)&sbuf[base + offs[s]];
#pragma unroll
                    for (int gi = 0; gi < NGI; ++gi)
                        acc[gi] = __builtin_amdgcn_mfma_f32_16x16x32_bf16(
                            bw[gi][s], a, acc[gi], 0, 0, 0);
                }

                int gxx = x0 + tx * 16 + col;
#pragma unroll
                for (int gi = 0; gi < NGI; ++gi) {
                    int co_g = gi * 16 + kg * 4;
                    if (co_g < COUT && gxx < W_) {
                        uint2 st;
                        st.x = packbf(acc[gi].x + bias_r[gi][0],
                                      acc[gi].y + bias_r[gi][1]);
                        st.y = packbf(acc[gi].z + bias_r[gi][2],
                                      acc[gi].w + bias_r[gi][3]);
                        *(uint2*)&out[((size_t)b * HW_ + (size_t)gy * W_ + gxx) *
                                          co_total + co_off + co_g] = st;
                    }
                }
            }
        }

        // ---- fused BN partial stats (gated only) ----
        if constexpr (MODE == 2) {
#pragma unroll
            for (int off = 1; off < 16; off <<= 1) {
#pragma unroll
                for (int r = 0; r < 4; ++r) {
                    bs[r] += __shfl_xor(bs[r], off);
                    bs2[r] += __shfl_xor(bs2[r], off);
                }
            }
            __shared__ float bsum[4][8], bsq[4][8];
            if (lane == 0) {
#pragma unroll
                for (int r = 0; r < 4; ++r) {
                    bsum[wv][r] = bs[r];
                    bsq[wv][r] = bs2[r];
                }
            }
            if (lane == 16) {
#pragma unroll
                for (int r = 0; r < 4; ++r) {
                    bsum[wv][4 + r] = bs[r];
                    bsq[wv][4 + r] = bs2[r];
                }
            }
            __syncthreads();
            if (tid < 8) {
                float s = 0.f, s2 = 0.f;
#pragma unroll
                for (int w = 0; w < 4; ++w) { s += bsum[w][tid]; s2 += bsq[w][tid]; }
                int bIdx = (img_base + b) * 190 + blockIdx.y * 10 + blockIdx.x;
                bnp[(size_t)bIdx * 8 + tid] = make_float2(s, s2);
            }
        }

        if (PIPE && i + 1 < NIMG) {
            stage_write((i + 1) & 1);
            __syncthreads();
        }
    }
}

// ---------------------------------------------------------------------------
// Fused cK trio as ONE composite 32-ch conv (planes x|up5|up10|up15) with
// NGI=2 column groups ({c5,c10}, {c15}), row-cached loop, and the same
// PIPE=2-image double-buffer + async-STAGE split.
// ---------------------------------------------------------------------------
template <int PIPE>
__global__ __launch_bounds__(256) void convc3_k(
    const unsigned short* __restrict__ src,
    const unsigned short* __restrict__ p5, const unsigned short* __restrict__ p10,
    const unsigned short* __restrict__ p15,
    const unsigned short* __restrict__ wpack,
    const float* __restrict__ bc5, const float* __restrict__ bc10,
    const float* __restrict__ bc15, unsigned short* __restrict__ out, int zimgs)
{
    constexpr int TH = 16;
    constexpr int NPX = (TH + 2) * 34;
    constexpr int NIMG = PIPE ? 2 : 1;
    __shared__ __align__(16) unsigned short s_in[(PIPE ? 2 : 1) * 4 * NPX * 8];

    int z = blockIdx.z;
    int x0 = blockIdx.x * 32, y0 = blockIdx.y * TH;
    int tid = threadIdx.x;
    int lane = tid & 63, wv = tid >> 6;
    bool interior = (x0 >= 1) && (x0 + 32 < W_) && (y0 >= 1) && (y0 + TH < H_);

    int oct = wv;  // wave-uniform plane

    u16x8 pre[10];
    auto stage_load = [&](int b) {
        const unsigned short* sb = src + (size_t)b * 8 * HW_;
        const unsigned short* pb5 = p5 + (size_t)b * 8 * 3600;
        const unsigned short* pb10 = p10 + (size_t)b * 8 * 900;
        const unsigned short* pb15 = p15 + (size_t)b * 8 * 400;
        if (interior) {
            const unsigned short* sb0 =
                sb + ((size_t)(y0 - 1) * W_ + (x0 - 1)) * 8;
#pragma unroll
            for (int k = 0; k < 10; ++k) {
                int px = lane + k * 64;
                u16x8 v = {0, 0, 0, 0, 0, 0, 0, 0};
                if (px < NPX) {
                    int y = px / 34;
                    if (oct == 0) {
                        v = *(const u16x8*)&sb0[(size_t)(px + y * 266) * 8];
                    } else {
                        int x = px - y * 34;
                        int gy = y0 - 1 + y, gx = x0 - 1 + x;
                        const unsigned short* pp =
                            (oct == 1) ? &pb5[((size_t)(gy / 5) * 60 + gx / 5) * 8]
                            : (oct == 2)
                                ? &pb10[((size_t)(gy / 10) * 30 + gx / 10) * 8]
                                : &pb15[((size_t)(gy / 15) * 20 + gx / 15) * 8];
                        v = *(const u16x8*)pp;
                    }
                }
                pre[k] = v;
            }
        } else {
#pragma unroll
            for (int k = 0; k < 10; ++k) {
                int px = lane + k * 64;
                u16x8 v = {0, 0, 0, 0, 0, 0, 0, 0};
                if (px < NPX) {
                    int y = px / 34, x = px - y * 34;
                    int gy = y0 + y - 1, gx = x0 + x - 1;
                    if (gy >= 0 && gy < H_ && gx >= 0 && gx < W_) {
                        if (oct == 0)
                            v = *(const u16x8*)&sb[((size_t)gy * W_ + gx) * 8];
                        else if (oct == 1)
                            v = *(const u16x8*)&pb5[((size_t)(gy / 5) * 60 +
                                                     gx / 5) * 8];
                        else if (oct == 2)
                            v = *(const u16x8*)&pb10[((size_t)(gy / 10) * 30 +
                                                      gx / 10) * 8];
                        else
                            v = *(const u16x8*)&pb15[((size_t)(gy / 15) * 20 +
                                                      gx / 15) * 8];
                    }
                }
                pre[k] = v;
            }
        }
    };
    auto stage_write = [&](int bsel) {
        unsigned short* sbuf = s_in + (size_t)bsel * (4 * NPX * 8);
#pragma unroll
        for (int k = 0; k < 10; ++k) {
            int px = lane + k * 64;
            if (px < NPX) *(u16x8*)&sbuf[(oct * NPX + px) * 8] = pre[k];
        }
    };

    bf16x8 bw[2][9];
#pragma unroll
    for (int g = 0; g < 2; ++g)
#pragma unroll
        for (int s = 0; s < 9; ++s)
            bw[g][s] = *(const bf16x8*)&wpack[((s * 2 + g) * 64 + lane) * 8];

    int col = lane & 15, kg = lane >> 4;
    float bias_r[2][4];
#pragma unroll
    for (int r = 0; r < 4; ++r) {
        bias_r[0][r] = (kg < 2) ? bc5[kg * 4 + r] : bc10[(kg - 2) * 4 + r];
        bias_r[1][r] = (kg < 2) ? bc15[kg * 4 + r] : 0.f;
    }

    stage_load(z);
    stage_write(0);
    __syncthreads();

#pragma unroll
    for (int i = 0; i < NIMG; ++i) {
        int b = z + i * zimgs;
        if (PIPE && i + 1 < NIMG) stage_load(z + (i + 1) * zimgs);
        unsigned short* sbuf = s_in + (size_t)(PIPE ? (i & 1) : 0) * (4 * NPX * 8);

        int myb = wv * (TH / 4);
#pragma unroll
        for (int tx = 0; tx < 2; ++tx) {
            int pbase = kg * NPX + tx * 16 + col;
            bf16x8 fr[3][3];
#pragma unroll
            for (int r = 0; r < 2; ++r)
#pragma unroll
                for (int dx = 0; dx < 3; ++dx)
                    fr[r][dx] =
                        *(const bf16x8*)&sbuf[(pbase + (myb + r) * 34 + dx) * 8];
#pragma unroll
            for (int ii = 0; ii < TH / 4; ++ii) {
#pragma unroll
                for (int dx = 0; dx < 3; ++dx)
                    fr[(ii + 2) % 3][dx] =
                        *(const bf16x8*)&sbuf[(pbase + (myb + ii + 2) * 34 + dx) * 8];

                f32x4 acc[2];
                acc[0] = {0.f, 0.f, 0.f, 0.f};
                acc[1] = {0.f, 0.f, 0.f, 0.f};
#pragma unroll
                for (int dy = 0; dy < 3; ++dy)
#pragma unroll
                    for (int dx = 0; dx < 3; ++dx) {
                        bf16x8 a = fr[(ii + dy) % 3][dx];
                        acc[0] = __builtin_amdgcn_mfma_f32_16x16x32_bf16(
                            bw[0][dy * 3 + dx], a, acc[0], 0, 0, 0);
                        acc[1] = __builtin_amdgcn_mfma_f32_16x16x32_bf16(
                            bw[1][dy * 3 + dx], a, acc[1], 0, 0, 0);
                    }

                int gy = y0 + myb + ii;
                int gxx = x0 + tx * 16 + col;
                if (gy < H_ && gxx < W_) {
                    size_t pxo = ((size_t)b * HW_ + (size_t)gy * W_ + gxx) * 24;
                    uint2 st0;
                    st0.x = packbf(acc[0].x + bias_r[0][0], acc[0].y + bias_r[0][1]);
                    st0.y = packbf(acc[0].z + bias_r[0][2], acc[0].w + bias_r[0][3]);
                    *(uint2*)&out[pxo + kg * 4] = st0;  // ch 0-15: c5|c10
                    if (kg < 2) {
                        uint2 st1;
                        st1.x = packbf(acc[1].x + bias_r[1][0],
                                       acc[1].y + bias_r[1][1]);
                        st1.y = packbf(acc[1].z + bias_r[1][2],
                                       acc[1].w + bias_r[1][3]);
                        *(uint2*)&out[pxo + 16 + kg * 4] = st1;  // ch 16-23: c15
                    }
                }
            }
        }

        if (PIPE && i + 1 < NIMG) {
            stage_write((i + 1) & 1);
            __syncthreads();
        }
    }
}

// ---------------------------------------------------------------------------
// Pools, NHWC. p5 from x; p10/p15 from p5 (hierarchical).
// ---------------------------------------------------------------------------
__global__ __launch_bounds__(256) void pool5_k(const unsigned short* __restrict__ x,
                                               unsigned short* __restrict__ p5,
                                               int n)
{
    int idx = blockIdx.x * 256 + threadIdx.x;
    if (idx >= n) return;
    int b = idx / 3600;
    int rem = idx - b * 3600;
    int i = rem / 60, j = rem - i * 60;
    const unsigned short* src =
        x + ((size_t)b * HW_ + (size_t)(i * 5) * W_ + j * 5) * 8;
    float ss[8] = {0, 0, 0, 0, 0, 0, 0, 0};
#pragma unroll
    for (int r = 0; r < 5; ++r)
#pragma unroll
        for (int c = 0; c < 5; ++c) {
            u16x8 v = *(const u16x8*)&src[((size_t)r * W_ + c) * 8];
#pragma unroll
            for (int k = 0; k < 8; ++k) ss[k] += b2f(v[k]);
        }
    uint4 st;
    st.x = packbf(ss[0] * 0.04f, ss[1] * 0.04f);
    st.y = packbf(ss[2] * 0.04f, ss[3] * 0.04f);
    st.z = packbf(ss[4] * 0.04f, ss[5] * 0.04f);
    st.w = packbf(ss[6] * 0.04f, ss[7] * 0.04f);
    *(uint4*)&p5[(size_t)idx * 8] = st;
}

template <int R, int OD>
__device__ __forceinline__ void poolr_body(const unsigned short* __restrict__ p5,
                                           unsigned short* __restrict__ po, int idx)
{
    int b = idx / (OD * OD);
    int rem = idx - b * OD * OD;
    int i = rem / OD, j = rem - i * OD;
    const unsigned short* src =
        p5 + ((size_t)b * 3600 + (size_t)(i * R) * 60 + j * R) * 8;
    float ss[8] = {0, 0, 0, 0, 0, 0, 0, 0};
    const float inv = 1.f / (R * R);
#pragma unroll
    for (int r = 0; r < R; ++r)
#pragma unroll
        for (int c = 0; c < R; ++c) {
            u16x8 v = *(const u16x8*)&src[((size_t)r * 60 + c) * 8];
#pragma unroll
            for (int k = 0; k < 8; ++k) ss[k] += b2f(v[k]);
        }
    uint4 st;
    st.x = packbf(ss[0] * inv, ss[1] * inv);
    st.y = packbf(ss[2] * inv, ss[3] * inv);
    st.z = packbf(ss[4] * inv, ss[5] * inv);
    st.w = packbf(ss[6] * inv, ss[7] * inv);
    *(uint4*)&po[(size_t)idx * 8] = st;
}

__global__ __launch_bounds__(256) void poolrs_k(const unsigned short* __restrict__ p5,
                                                unsigned short* __restrict__ p10,
                                                unsigned short* __restrict__ p15,
                                                int n10, int n15)
{
    int idx = blockIdx.x * 256 + threadIdx.x;
    if (idx < n10) {
        poolr_body<2, 30>(p5, p10, idx);
    } else {
        idx -= n10;
        if (idx < n15) poolr_body<3, 20>(p5, p15, idx);
    }
}

// ---------------------------------------------------------------------------
// Stage A: collapse NPART block-partials to 64 rows (parallel, coalesced).
// ---------------------------------------------------------------------------
__global__ __launch_bounds__(256) void reduce_parts_k(
    const float2* __restrict__ parts, float2* __restrict__ parts2)
{
    int k = blockIdx.x;
    int tid = threadIdx.x;
    int c = tid & 7, j = tid >> 3;  // j in 0..31
    float s = 0.f, s2 = 0.f;
    for (int r = j; r < NPB; r += 32) {
        float2 p = parts[((size_t)k * NPB + r) * 8 + c];
        s += p.x;
        s2 += p.y;
    }
    __shared__ float2 red[256];
    red[tid] = make_float2(s, s2);
    __syncthreads();
    if (tid < 8) {
        float a = 0.f, b = 0.f;
        for (int q = 0; q < 32; ++q) {
            float2 p = red[q * 8 + tid];
            a += p.x;
            b += p.y;
        }
        parts2[(size_t)k * 8 + tid] = make_float2(a, b);
    }
}

// Stage B: reduce 64 rows, fold BN into conv11 weights; wfold[t*8+ci], [72]=bias.
__global__ __launch_bounds__(256) void stats_fold_k(
    const float2* __restrict__ parts2, const float* __restrict__ bn_w,
    const float* __restrict__ bn_b, const float* __restrict__ w11,
    const float* __restrict__ b11, float* __restrict__ wfold)
{
    __shared__ float sc[8], tc[8];
    __shared__ float2 acc8[8];
    int tid = threadIdx.x;
    int c = tid >> 5, sl = tid & 31;
    float s = 0.f, s2 = 0.f;
    for (int i = sl; i < 64; i += 32) {
        float2 p = parts2[(size_t)i * 8 + c];
        s += p.x;
        s2 += p.y;
    }
#pragma unroll
    for (int off = 16; off > 0; off >>= 1) {
        s += __shfl_down(s, off, 32);
        s2 += __shfl_down(s2, off, 32);
    }
    if (sl == 0) acc8[c] = make_float2(s, s2);
    __syncthreads();
    if (tid < 8) {
        double ds = acc8[tid].x, ds2 = acc8[tid].y;
        double N = (double)NBATCH * HW_;
        double mean = ds / N;
        double var = ds2 / N - mean * mean;
        float rstd = (float)(1.0 / sqrt(var + 1e-5));
        float scv = bn_w[tid] * rstd;
        sc[tid] = scv;
        tc[tid] = bn_b[tid] - (float)mean * scv;
    }
    __syncthreads();
    if (tid < 72) {
        int t = tid >> 3, ci = tid & 7;
        wfold[tid] = w11[ci * 9 + t] * sc[ci];
    }
    if (tid == 72) {
        float a = b11[0];
        for (int i = 0; i < 72; ++i) a += w11[i] * tc[i / 9];
        wfold[72] = a;
    }
}

// ---------------------------------------------------------------------------
// Final: att = sigmoid(conv 8->1 over NHWC gated), blend with im (NCHW fp32).
// ---------------------------------------------------------------------------
__global__ __launch_bounds__(256) void final_k(
    const unsigned short* __restrict__ gated, const float* __restrict__ wf,
    const float* __restrict__ im, const float* __restrict__ gamma,
    float* __restrict__ out)
{
    __shared__ __align__(16) unsigned short s_g[1156 * 8];
    __shared__ float s_w[80];

    int b = blockIdx.z;
    int x0 = blockIdx.x * 32, y0 = blockIdx.y * 32;
    int tid = threadIdx.x;
    bool interior = (x0 >= 1) && (x0 + 32 < W_) && (y0 >= 1) && (y0 + 32 < H_);

    if (tid < 73) s_w[tid] = wf[tid];

    const unsigned short* gb = gated + (size_t)b * HW_ * 8;
    if (interior) {
        const unsigned short* gb0 = gb + ((size_t)(y0 - 1) * W_ + (x0 - 1)) * 8;
        for (int e = tid; e < 1156; e += 256) {
            int y = e / 34;
            u16x8 v = *(const u16x8*)&gb0[(size_t)(e + y * 266) * 8];
            *(u16x8*)&s_g[e * 8] = v;
        }
    } else {
        for (int e = tid; e < 1156; e += 256) {
            int y = e / 34, x = e - y * 34;
            int gy = y0 + y - 1, gx = x0 + x - 1;
            u16x8 v = {0, 0, 0, 0, 0, 0, 0, 0};
            if (gy >= 0 && gy < H_ && gx >= 0 && gx < W_)
                v = *(const u16x8*)&gb[((size_t)gy * W_ + gx) * 8];
            *(u16x8*)&s_g[e * 8] = v;
        }
    }
    __syncthreads();

    int qx = (tid & 15) * 2, qy = (tid >> 4) * 2;
    float f[4];
    float gm = *gamma;
#pragma unroll
    for (int p = 0; p < 4; ++p) {
        int ly = qy + (p >> 1), lx = qx + (p & 1);
        float acc = s_w[72];
#pragma unroll
        for (int t = 0; t < 9; ++t) {
            u16x8 n = *(const u16x8*)&s_g[((ly + t / 3) * 34 + lx + t % 3) * 8];
#pragma unroll
            for (int ci = 0; ci < 8; ++ci) acc += b2f(n[ci]) * s_w[t * 8 + ci];
        }
        f[p] = (1.f - gm) + gm * sigm(acc);
    }

    int px = x0 + qx, py = y0 + qy;
    if (px < W_) {
#pragma unroll
        for (int ch = 0; ch < 3; ++ch) {
            const float* imb = im + ((size_t)b * 3 + ch) * HW_;
            float* ob = out + ((size_t)b * 3 + ch) * HW_;
#pragma unroll
            for (int pr = 0; pr < 2; ++pr) {
                if (py + pr < H_) {
                    float2 iv = *(const float2*)&imb[(size_t)(py + pr) * W_ + px];
                    float2 ov;
                    ov.x = iv.x * f[pr * 2 + 0];
                    ov.y = iv.y * f[pr * 2 + 1];
                    *(float2*)&ob[(size_t)(py + pr) * W_ + px] = ov;
                }
            }
        }
    }
}

// ---------------------------------------------------------------------------

extern "C" void kernel_launch(void* const* d_in, const int* in_sizes, int n_in,
                              void* d_out, int out_size, void* d_ws,
                              size_t ws_size, hipStream_t stream)
{
    (void)in_sizes; (void)n_in; (void)out_size;

    const float* im  = (const float*)d_in[0];
    const float* w1  = (const float*)d_in[1];
    const float* b1  = (const float*)d_in[2];
    const float* w2  = (const float*)d_in[3];
    const float* b2  = (const float*)d_in[4];
    const float* w3  = (const float*)d_in[5];
    const float* b3  = (const float*)d_in[6];
    const float* w4  = (const float*)d_in[7];
    const float* b4  = (const float*)d_in[8];
    const float* w5  = (const float*)d_in[9];
    const float* b5  = (const float*)d_in[10];
    const float* wc5 = (const float*)d_in[11];
    const float* bc5 = (const float*)d_in[12];
    const float* wc10= (const float*)d_in[13];
    const float* bc10= (const float*)d_in[14];
    const float* wc15= (const float*)d_in[15];
    const float* bc15= (const float*)d_in[16];
    const float* wg  = (const float*)d_in[17];
    const float* bg  = (const float*)d_in[18];
    const float* wm  = (const float*)d_in[19];
    const float* bm  = (const float*)d_in[20];
    const float* bnw = (const float*)d_in[21];
    const float* bnb = (const float*)d_in[22];
    const float* w11 = (const float*)d_in[23];
    const float* b11 = (const float*)d_in[24];
    const float* gam = (const float*)d_in[25];
    float* out = (float*)d_out;

    // ---- workspace plan (chunked batch; deterministic in ws_size) ----------
    const size_t GATED_B = 46080000;
    const size_t PER_IMG = 1440000 + 2880000 + 5760000 + 57600 + 14400 + 6656;
    const size_t MISC    = 1048576;
    int c = 32;
    while (c > 1 && GATED_B + MISC + (size_t)c * PER_IMG + 2048 > ws_size)
        c >>= 1;

    char* p = (char*)d_ws;
    auto take = [&](size_t bytes) {
        char* r = p;
        p += (bytes + 255) & ~(size_t)255;
        return r;
    };
    unsigned short* GATED = (unsigned short*)take(GATED_B);
    unsigned short* A   = (unsigned short*)take((size_t)c * 1440000);
    unsigned short* Bb  = (unsigned short*)take((size_t)c * 2880000);
    unsigned short* C   = (unsigned short*)take((size_t)c * 5760000);
    unsigned short* P5  = (unsigned short*)take((size_t)c * 57600);
    unsigned short* P10 = (unsigned short*)take((size_t)c * 14400);
    unsigned short* P15 = (unsigned short*)take((size_t)c * 6656);
    float2* parts  = (float2*)take((size_t)NPART * 8 * sizeof(float2));
    float2* parts2 = (float2*)take(64 * 8 * sizeof(float2));
    float*  wfold  = (float*)take(512);
    unsigned short* WP = (unsigned short*)take(65536);

    unsigned short* PK2 = WP;            // conv2: 3 steps
    unsigned short* PK3 = WP + 2048;     // conv3: 5x2
    unsigned short* PK4 = WP + 8192;     // conv4: 9
    unsigned short* PK5 = WP + 13312;    // conv5: 5
    unsigned short* PKc = WP + 16384;    // convc composite: 9x2
    unsigned short* PKg = WP + 25600;    // gated: 9
    unsigned short* PK1 = WP + 30720;    // conv1: 3

    dim3 blk(256);

    pack_all_k<<<dim3(7), blk, 0, stream>>>(w1, w2, w3, w4, w5, wc5, wc10, wc15,
                                            wg, wm, WP);

    int zi = (c >= 2) ? (c / 2) : 1;
    bool pipe = (c >= 2);

    for (int b0 = 0; b0 < NBATCH; b0 += c) {
        dim3 g32(10, 10, c);    // TH=32 kernels
        dim3 g16(10, 19, c);    // TH=16, unpipelined fallback
        dim3 g16p(10, 19, zi);  // TH=16, 2-image pipelined
        const float* imc = im + (size_t)b0 * 3 * HW_;

        mfconv_k<8, 8, 8, 1, 3, 32, 0><<<g32, blk, 0, stream>>>(
            (const unsigned short*)imc, PK1, b1, nullptr, A, 8, 0, nullptr, 0, c);
        mfconv_k<8, 8, 16, 1, 0, 32, 0><<<g32, blk, 0, stream>>>(
            A, PK2, b2, nullptr, Bb, 16, 0, nullptr, 0, c);
        mfconv_k<16, 16, 32, 2, 0, 32, 0><<<g32, blk, 0, stream>>>(
            Bb, PK3, b3, nullptr, C, 32, 0, nullptr, 0, c);

        if (pipe)
            mfconv_k<32, 32, 16, 1, 0, 16, 1><<<g16p, blk, 0, stream>>>(
                C, PK4, b4, nullptr, Bb, 16, 0, nullptr, 0, zi);
        else
            mfconv_k<32, 32, 16, 1, 0, 16, 0><<<g16, blk, 0, stream>>>(
                C, PK4, b4, nullptr, Bb, 16, 0, nullptr, 0, c);

        mfconv_k<16, 16, 8, 1, 0, 32, 0><<<g32, blk, 0, stream>>>(
            Bb, PK5, b5, nullptr, A, 8, 0, nullptr, 0, c);

        int n5 = c * 3600, n10 = c * 900, n15 = c * 400;
        pool5_k<<<dim3((n5 + 255) / 256), blk, 0, stream>>>(A, P5, n5);
        poolrs_k<<<dim3((n10 + n15 + 255) / 256), blk, 0, stream>>>(P5, P10, P15,
                                                                    n10, n15);

        if (pipe)
            convc3_k<1><<<g16p, blk, 0, stream>>>(A, P5, P10, P15, PKc, bc5,
                                                  bc10, bc15, C, zi);
        else
            convc3_k<0><<<g16, blk, 0, stream>>>(A, P5, P10, P15, PKc, bc5,
                                                 bc10, bc15, C, c);

        if (pipe)
            mfconv_k<24, 32, 16, 1, 2, 16, 1><<<g16p, blk, 0, stream>>>(
                C, PKg, bg, bm, GATED + (size_t)b0 * HW_ * 8, 8, 0, parts, b0, zi);
        else
            mfconv_k<24, 32, 16, 1, 2, 16, 0><<<g16, blk, 0, stream>>>(
                C, PKg, bg, bm, GATED + (size_t)b0 * HW_ * 8, 8, 0, parts, b0, c);
    }

    reduce_parts_k<<<dim3(64), blk, 0, stream>>>(parts, parts2);
    stats_fold_k<<<dim3(1), blk, 0, stream>>>(parts2, bnw, bnb, w11, b11, wfold);
    final_k<<<dim3(10, 10, NBATCH), blk, 0, stream>>>(GATED, wfold, im, gam,
                                                      out);
}

// Round 12
// 419.147 us; speedup vs baseline: 1.0705x; 1.0705x over previous
//
#include <hip/hip_runtime.h>
#include <hip/hip_bf16.h>
#include <math.h>

typedef __hip_bfloat16 bf16;
typedef __attribute__((ext_vector_type(8))) __bf16 bf16x8;
typedef __attribute__((ext_vector_type(8))) unsigned short u16x8;
typedef __attribute__((ext_vector_type(4))) float f32x4;

#define H_ 300
#define W_ 300
#define HW_ 90000
#define NBATCH 32
#define NPART (NBATCH * 190)   // gated BN partials: one per gated (image,tile)
#define NPB 95                 // partial rows per reduce_parts block (6080/64)

__device__ __forceinline__ float b2f(unsigned short u) {
    return __uint_as_float((unsigned int)u << 16);
}
__device__ __forceinline__ unsigned short f2u(float v) {
    bf16 b = __float2bfloat16(v);
    return *reinterpret_cast<unsigned short*>(&b);
}
__device__ __forceinline__ float sigm(float x) { return 1.f / (1.f + __expf(-x)); }
// HW packed fp32->bf16 pair (RNE), 1 instr vs ~10 for the manual sequence.
__device__ __forceinline__ unsigned int packbf(float a, float b) {
    unsigned int r;
    asm("v_cvt_pk_bf16_f32 %0, %1, %2" : "=v"(r) : "v"(a), "v"(b));
    return r;
}
// Async global->LDS DMA, 16B per lane. LDS dest = wave-uniform base + lane*16;
// global src is per-lane. vmcnt drained by the compiler before s_barrier.
__device__ __forceinline__ void async_cp16(void* lds_base, const void* g) {
    __builtin_amdgcn_global_load_lds(
        (const __attribute__((address_space(1))) unsigned int*)g,
        (__attribute__((address_space(3))) unsigned int*)lds_base, 16, 0, 0);
}

// ---------------------------------------------------------------------------
// All weight prepacks in ONE launch (7 blocks). Fragment order: A operand,
// row = lane&15 = co, k = (lane>>4)*8+j; pack[step][g][lane][j] bf16.
// Block 4 is the convc composite (see convc3_k).
// ---------------------------------------------------------------------------
__global__ void pack_all_k(
    const float* __restrict__ w1, const float* __restrict__ w2,
    const float* __restrict__ w3, const float* __restrict__ w4,
    const float* __restrict__ w5, const float* __restrict__ wc5,
    const float* __restrict__ wc10, const float* __restrict__ wc15,
    const float* __restrict__ wg, const float* __restrict__ wm,
    unsigned short* __restrict__ WP)
{
    const float *a = nullptr, *bsec = nullptr;
    int cs = 999, CO = 0, CI = 0, CP = 8, NS = 3, NG = 1, off = 0, special = 0;
    switch (blockIdx.x) {
        case 0: a = w2;  CO = 16; CI = 8;  CP = 8;  NS = 3; off = 0;     break;
        case 1: a = w3;  CO = 32; CI = 16; CP = 16; NS = 5; NG = 2; off = 2048;  break;
        case 2: a = w4;  CO = 16; CI = 32; CP = 32; NS = 9; off = 8192;  break;
        case 3: a = w5;  CO = 8;  CI = 16; CP = 16; NS = 5; off = 13312; break;
        case 4: special = 1; CO = 32; CI = 32; CP = 32; NS = 9; NG = 2;
                off = 16384; break;
        case 5: a = wg; bsec = wm; cs = 8; CO = 16; CI = 24; CP = 32; NS = 9;
                off = 25600; break;
        case 6: a = w1;  CO = 8;  CI = 3;  CP = 8;  NS = 3; off = 30720; break;
    }
    unsigned short* outp = WP + off;
    int TPK = 32 / CP;
    int total = NS * NG * 512;
    for (int idx = threadIdx.x; idx < total; idx += 256) {
        int j = idx & 7;
        int lane = (idx >> 3) & 63;
        int g = (idx >> 9) % NG;
        int s = idx / (512 * NG);
        int col = lane & 15, kg = lane >> 4;
        int kk = kg * 8 + j;
        int tt = kk / CP, ci = kk % CP;
        int tap = s * TPK + tt;
        float v = 0.f;
        if (special) {
            int o = ci >> 3, c8 = ci & 7;
            int convid = (g == 0) ? (col < 8 ? 0 : 1) : (col < 8 ? 2 : -1);
            if (tap < 9 && convid >= 0) {
                const float* wc = (convid == 0) ? wc5 : (convid == 1) ? wc10 : wc15;
                int colc = col & 7;
                if (o == 0) v = wc[(colc * 16 + c8) * 9 + tap];
                else if (o == convid + 1) v = wc[(colc * 16 + 8 + c8) * 9 + tap];
            }
        } else {
            int co = g * 16 + col;
            if (tap < 9 && ci < CI && co < CO)
                v = (co >= cs) ? bsec[((co - cs) * CI + ci) * 9 + tap]
                               : a[(co * CI + ci) * 9 + tap];
        }
        outp[idx] = f2u(v);
    }
}

// ---------------------------------------------------------------------------
// MFMA implicit-GEMM 3x3 conv, NHWC in/out. Tile 32xTH px, 4 waves.
// Octet-planar LDS s_in[oct][(TH+2)*34 px][8ch]. OCT==4 uses a ROW-CACHED
// inner loop (3 new ds_reads/row instead of 9). INTERIOR staging uses
// global_load_lds width-16 DMA (no VGPR round trip; loads issued back-to-back
// for max memory-level parallelism). Boundary blocks use the register path.
// MODE 0: plain. MODE 2: gated (rows 0-7 g, 8-15 m; out = g*sigm(m)) and
// fused BN partial stats (one float2x8 per (image,tile)). MODE 3: conv1.
// ---------------------------------------------------------------------------
template <int CIN, int CINP, int COUT, int NGI, int MODE, int TH>
__global__ __launch_bounds__(256) void mfconv_k(
    const unsigned short* __restrict__ src,
    const unsigned short* __restrict__ wpack,
    const float* __restrict__ bias0, const float* __restrict__ bias1,
    unsigned short* __restrict__ out, int co_total, int co_off,
    float2* __restrict__ bnp, int img_base)
{
    constexpr int TPK = 32 / CINP;
    constexpr int NSTEP = (9 + TPK - 1) / TPK;
    constexpr int OCT = CINP / 8;
    constexpr int NPX = (TH + 2) * 34;
    constexpr int STRIDE = 256 / OCT;   // px advance per k-step (per wave set)

    __shared__ __align__(16) unsigned short s_in[OCT * NPX * 8];

    int b = blockIdx.z;
    int x0 = blockIdx.x * 32, y0 = blockIdx.y * TH;
    int tid = threadIdx.x;
    int lane = tid & 63, wv = tid >> 6;
    bool interior = (x0 >= 1) && (x0 + 32 < W_) && (y0 >= 1) && (y0 + TH < H_);

    int oct = (OCT == 1) ? 0 : (wv % OCT);
    int phase = (OCT == 4) ? 0 : (wv / OCT);
    bool voct = (CIN == CINP) || (oct * 8 < CIN);

    // ---- staging ----
    if (MODE == 3) {
        const float* sf = reinterpret_cast<const float*>(src) + (size_t)b * 3 * HW_;
        if (interior) {
            const float* sf0 = sf + (size_t)(y0 - 1) * W_ + (x0 - 1);
            for (int e = tid; e < NPX; e += 256) {
                int y = e / 34;
                size_t o = (size_t)e + (size_t)y * 266;
                u16x8 v = {0, 0, 0, 0, 0, 0, 0, 0};
                v[0] = f2u(sf0[o]);
                v[1] = f2u(sf0[HW_ + o]);
                v[2] = f2u(sf0[2 * HW_ + o]);
                *(u16x8*)&s_in[e * 8] = v;
            }
        } else {
            for (int e = tid; e < NPX; e += 256) {
                int y = e / 34, x = e - y * 34;
                int gy = y0 + y - 1, gx = x0 + x - 1;
                u16x8 v = {0, 0, 0, 0, 0, 0, 0, 0};
                if (gy >= 0 && gy < H_ && gx >= 0 && gx < W_) {
                    size_t o = (size_t)gy * W_ + gx;
                    v[0] = f2u(sf[o]);
                    v[1] = f2u(sf[HW_ + o]);
                    v[2] = f2u(sf[2 * HW_ + o]);
                }
                *(u16x8*)&s_in[e * 8] = v;
            }
        }
    } else {
        const unsigned short* sb = src + (size_t)b * CIN * HW_;
        if (interior) {
            if (voct) {
                // async DMA path: uniform LDS base + lane*16, per-lane g addr
                const unsigned short* sb0 =
                    sb + ((size_t)(y0 - 1) * W_ + (x0 - 1)) * CIN + oct * 8;
#pragma unroll
                for (int pxb = 0; pxb < NPX; pxb += STRIDE) {
                    int base = phase * 64 + pxb;
                    if (base >= NPX) break;
                    int px = base + lane;
                    if (px < NPX) {
                        int y = px / 34;
                        async_cp16(&s_in[(oct * NPX + base) * 8],
                                   &sb0[(size_t)(px + y * 266) * CIN]);
                    }
                }
            } else {
                u16x8 z8 = {0, 0, 0, 0, 0, 0, 0, 0};
                for (int px = lane + phase * 64; px < NPX; px += STRIDE)
                    *(u16x8*)&s_in[(oct * NPX + px) * 8] = z8;
            }
        } else {
            for (int px = lane + phase * 64; px < NPX; px += STRIDE) {
                int y = px / 34, x = px - y * 34;
                int gy = y0 + y - 1, gx = x0 + x - 1;
                u16x8 v = {0, 0, 0, 0, 0, 0, 0, 0};
                if (gy >= 0 && gy < H_ && gx >= 0 && gx < W_ && voct)
                    v = *(const u16x8*)&sb[((size_t)gy * W_ + gx) * CIN + oct * 8];
                *(u16x8*)&s_in[(oct * NPX + px) * 8] = v;
            }
        }
    }

    // ---- weight fragments (NGI groups) ----
    bf16x8 bw[NGI][NSTEP];
#pragma unroll
    for (int gi = 0; gi < NGI; ++gi)
#pragma unroll
        for (int s = 0; s < NSTEP; ++s)
            bw[gi][s] = *(const bf16x8*)&wpack[((s * NGI + gi) * 64 + lane) * 8];

    int col = lane & 15, kg = lane >> 4;

    float bias_r[NGI][4];
#pragma unroll
    for (int gi = 0; gi < NGI; ++gi)
#pragma unroll
        for (int r = 0; r < 4; ++r) {
            if (MODE == 2)
                bias_r[0][r] = (kg < 2) ? bias0[kg * 4 + r] : bias1[(kg - 2) * 4 + r];
            else {
                int co_l = gi * 16 + kg * 4 + r;
                bias_r[gi][r] = (co_l < COUT) ? bias0[co_l] : 0.f;
            }
        }

    float bs[4] = {0.f, 0.f, 0.f, 0.f}, bs2[4] = {0.f, 0.f, 0.f, 0.f};

    __syncthreads();

    if constexpr (OCT == 4) {
        // ---- row-cached inner loop (TPK==1: step s == tap s) ----
        int myb = wv * (TH / 4);
#pragma unroll
        for (int tx = 0; tx < 2; ++tx) {
            int pbase = kg * NPX + tx * 16 + col;
            bf16x8 fr[3][3];
#pragma unroll
            for (int r = 0; r < 2; ++r)
#pragma unroll
                for (int dx = 0; dx < 3; ++dx)
                    fr[r][dx] =
                        *(const bf16x8*)&s_in[(pbase + (myb + r) * 34 + dx) * 8];
#pragma unroll
            for (int ii = 0; ii < TH / 4; ++ii) {
#pragma unroll
                for (int dx = 0; dx < 3; ++dx)
                    fr[(ii + 2) % 3][dx] =
                        *(const bf16x8*)&s_in[(pbase + (myb + ii + 2) * 34 + dx) * 8];

                f32x4 acc[NGI];
#pragma unroll
                for (int gi = 0; gi < NGI; ++gi) acc[gi] = {0.f, 0.f, 0.f, 0.f};
#pragma unroll
                for (int dy = 0; dy < 3; ++dy)
#pragma unroll
                    for (int dx = 0; dx < 3; ++dx) {
                        bf16x8 a = fr[(ii + dy) % 3][dx];
#pragma unroll
                        for (int gi = 0; gi < NGI; ++gi)
                            acc[gi] = __builtin_amdgcn_mfma_f32_16x16x32_bf16(
                                bw[gi][dy * 3 + dx], a, acc[gi], 0, 0, 0);
                    }

                int gy = y0 + myb + ii;
                int gxx = x0 + tx * 16 + col;
                if (gy < H_) {
                    if (MODE == 2) {
                        float v0 = acc[0].x + bias_r[0][0];
                        float v1 = acc[0].y + bias_r[0][1];
                        float v2 = acc[0].z + bias_r[0][2];
                        float v3 = acc[0].w + bias_r[0][3];
                        float m0 = __shfl_xor(v0, 32), m1 = __shfl_xor(v1, 32);
                        float m2 = __shfl_xor(v2, 32), m3 = __shfl_xor(v3, 32);
                        if (kg < 2 && gxx < W_) {
                            float o0 = v0 * sigm(m0), o1 = v1 * sigm(m1);
                            float o2 = v2 * sigm(m2), o3 = v3 * sigm(m3);
                            uint2 st;
                            st.x = packbf(o0, o1);
                            st.y = packbf(o2, o3);
                            *(uint2*)&out[(((size_t)b * HW_ + (size_t)gy * W_ +
                                            gxx) * 8) + kg * 4] = st;
                            bs[0] += o0; bs2[0] += o0 * o0;
                            bs[1] += o1; bs2[1] += o1 * o1;
                            bs[2] += o2; bs2[2] += o2 * o2;
                            bs[3] += o3; bs2[3] += o3 * o3;
                        }
                    } else {
#pragma unroll
                        for (int gi = 0; gi < NGI; ++gi) {
                            int co_g = gi * 16 + kg * 4;
                            if (co_g < COUT && gxx < W_) {
                                uint2 st;
                                st.x = packbf(acc[gi].x + bias_r[gi][0],
                                              acc[gi].y + bias_r[gi][1]);
                                st.y = packbf(acc[gi].z + bias_r[gi][2],
                                              acc[gi].w + bias_r[gi][3]);
                                *(uint2*)&out[((size_t)b * HW_ +
                                               (size_t)gy * W_ + gxx) *
                                                  co_total + co_off + co_g] = st;
                            }
                        }
                    }
                }
            }
        }
    } else {
        // ---- generic loop for OCT<=2 ----
        int offs[NSTEP];
#pragma unroll
        for (int s = 0; s < NSTEP; ++s) {
            int t = s * TPK + kg / OCT;
            if (t > 8) t = 8;  // padded taps: weights are zero there
            offs[s] = ((t / 3) * 34 + (t % 3)) * 8 + (kg % OCT) * (NPX * 8);
        }

#pragma unroll
        for (int i = 0; i < TH / 2; ++i) {
            int m = wv * (TH / 2) + i;
            int my = m >> 1, tx = m & 1;
            int gy = y0 + my;
            if (gy >= H_) continue;  // wave-uniform
            int base = (my * 34 + tx * 16 + col) * 8;

            f32x4 acc[NGI];
#pragma unroll
            for (int gi = 0; gi < NGI; ++gi) acc[gi] = {0.f, 0.f, 0.f, 0.f};
#pragma unroll
            for (int s = 0; s < NSTEP; ++s) {
                bf16x8 a = *(const bf16x8*)&s_in[base + offs[s]];
#pragma unroll
                for (int gi = 0; gi < NGI; ++gi)
                    acc[gi] = __builtin_amdgcn_mfma_f32_16x16x32_bf16(
                        bw[gi][s], a, acc[gi], 0, 0, 0);
            }

            int gxx = x0 + tx * 16 + col;
#pragma unroll
            for (int gi = 0; gi < NGI; ++gi) {
                int co_g = gi * 16 + kg * 4;
                if (co_g < COUT && gxx < W_) {
                    uint2 st;
                    st.x = packbf(acc[gi].x + bias_r[gi][0],
                                  acc[gi].y + bias_r[gi][1]);
                    st.y = packbf(acc[gi].z + bias_r[gi][2],
                                  acc[gi].w + bias_r[gi][3]);
                    *(uint2*)&out[((size_t)b * HW_ + (size_t)gy * W_ + gxx) *
                                      co_total + co_off + co_g] = st;
                }
            }
        }
    }

    // ---- fused BN partial stats (gated only): block-local, deterministic ----
    if constexpr (MODE == 2) {
#pragma unroll
        for (int off = 1; off < 16; off <<= 1) {
#pragma unroll
            for (int r = 0; r < 4; ++r) {
                bs[r] += __shfl_xor(bs[r], off);
                bs2[r] += __shfl_xor(bs2[r], off);
            }
        }
        __shared__ float bsum[4][8], bsq[4][8];
        if (lane == 0) {
#pragma unroll
            for (int r = 0; r < 4; ++r) { bsum[wv][r] = bs[r]; bsq[wv][r] = bs2[r]; }
        }
        if (lane == 16) {
#pragma unroll
            for (int r = 0; r < 4; ++r) {
                bsum[wv][4 + r] = bs[r];
                bsq[wv][4 + r] = bs2[r];
            }
        }
        __syncthreads();
        if (tid < 8) {
            float s = 0.f, s2 = 0.f;
#pragma unroll
            for (int w = 0; w < 4; ++w) { s += bsum[w][tid]; s2 += bsq[w][tid]; }
            int bIdx = (img_base + b) * 190 + blockIdx.y * 10 + blockIdx.x;
            bnp[(size_t)bIdx * 8 + tid] = make_float2(s, s2);
        }
    }
}

// ---------------------------------------------------------------------------
// Fused cK trio as ONE composite 32-ch conv (planes x|up5|up10|up15) with
// NGI=2 column groups ({c5,c10}, {c15}) and the row-cached inner loop.
// Interior x-plane staged via global_load_lds DMA; pool planes via registers.
// ---------------------------------------------------------------------------
__global__ __launch_bounds__(256) void convc3_k(
    const unsigned short* __restrict__ src,
    const unsigned short* __restrict__ p5, const unsigned short* __restrict__ p10,
    const unsigned short* __restrict__ p15,
    const unsigned short* __restrict__ wpack,
    const float* __restrict__ bc5, const float* __restrict__ bc10,
    const float* __restrict__ bc15, unsigned short* __restrict__ out)
{
    constexpr int TH = 16;
    constexpr int NPX = (TH + 2) * 34;
    __shared__ __align__(16) unsigned short s_in[4 * NPX * 8];

    int b = blockIdx.z;
    int x0 = blockIdx.x * 32, y0 = blockIdx.y * TH;
    int tid = threadIdx.x;
    int lane = tid & 63, wv = tid >> 6;
    bool interior = (x0 >= 1) && (x0 + 32 < W_) && (y0 >= 1) && (y0 + TH < H_);

    const unsigned short* sb = src + (size_t)b * 8 * HW_;
    const unsigned short* pb5 = p5 + (size_t)b * 8 * 3600;
    const unsigned short* pb10 = p10 + (size_t)b * 8 * 900;
    const unsigned short* pb15 = p15 + (size_t)b * 8 * 400;

    int oct = wv;  // wave-uniform plane
    if (interior) {
        if (oct == 0) {
            const unsigned short* sb0 =
                sb + ((size_t)(y0 - 1) * W_ + (x0 - 1)) * 8;
#pragma unroll
            for (int base = 0; base < NPX; base += 64) {
                int px = base + lane;
                if (px < NPX) {
                    int y = px / 34;
                    async_cp16(&s_in[(size_t)base * 8],
                               &sb0[(size_t)(px + y * 266) * 8]);
                }
            }
        } else {
            for (int px = lane; px < NPX; px += 64) {
                int y = px / 34, x = px - y * 34;
                int gy = y0 - 1 + y, gx = x0 - 1 + x;
                const unsigned short* pp =
                    (oct == 1) ? &pb5[((size_t)(gy / 5) * 60 + gx / 5) * 8]
                    : (oct == 2) ? &pb10[((size_t)(gy / 10) * 30 + gx / 10) * 8]
                                 : &pb15[((size_t)(gy / 15) * 20 + gx / 15) * 8];
                *(u16x8*)&s_in[(oct * NPX + px) * 8] = *(const u16x8*)pp;
            }
        }
    } else {
        for (int px = lane; px < NPX; px += 64) {
            int y = px / 34, x = px - y * 34;
            int gy = y0 + y - 1, gx = x0 + x - 1;
            u16x8 v = {0, 0, 0, 0, 0, 0, 0, 0};
            if (gy >= 0 && gy < H_ && gx >= 0 && gx < W_) {
                if (oct == 0)
                    v = *(const u16x8*)&sb[((size_t)gy * W_ + gx) * 8];
                else if (oct == 1)
                    v = *(const u16x8*)&pb5[((size_t)(gy / 5) * 60 + gx / 5) * 8];
                else if (oct == 2)
                    v = *(const u16x8*)&pb10[((size_t)(gy / 10) * 30 + gx / 10) * 8];
                else
                    v = *(const u16x8*)&pb15[((size_t)(gy / 15) * 20 + gx / 15) * 8];
            }
            *(u16x8*)&s_in[(oct * NPX + px) * 8] = v;
        }
    }

    bf16x8 bw[2][9];
#pragma unroll
    for (int g = 0; g < 2; ++g)
#pragma unroll
        for (int s = 0; s < 9; ++s)
            bw[g][s] = *(const bf16x8*)&wpack[((s * 2 + g) * 64 + lane) * 8];

    int col = lane & 15, kg = lane >> 4;
    float bias_r[2][4];
#pragma unroll
    for (int r = 0; r < 4; ++r) {
        bias_r[0][r] = (kg < 2) ? bc5[kg * 4 + r] : bc10[(kg - 2) * 4 + r];
        bias_r[1][r] = (kg < 2) ? bc15[kg * 4 + r] : 0.f;
    }

    __syncthreads();

    int myb = wv * (TH / 4);
#pragma unroll
    for (int tx = 0; tx < 2; ++tx) {
        int pbase = kg * NPX + tx * 16 + col;
        bf16x8 fr[3][3];
#pragma unroll
        for (int r = 0; r < 2; ++r)
#pragma unroll
            for (int dx = 0; dx < 3; ++dx)
                fr[r][dx] = *(const bf16x8*)&s_in[(pbase + (myb + r) * 34 + dx) * 8];
#pragma unroll
        for (int ii = 0; ii < TH / 4; ++ii) {
#pragma unroll
            for (int dx = 0; dx < 3; ++dx)
                fr[(ii + 2) % 3][dx] =
                    *(const bf16x8*)&s_in[(pbase + (myb + ii + 2) * 34 + dx) * 8];

            f32x4 acc[2];
            acc[0] = {0.f, 0.f, 0.f, 0.f};
            acc[1] = {0.f, 0.f, 0.f, 0.f};
#pragma unroll
            for (int dy = 0; dy < 3; ++dy)
#pragma unroll
                for (int dx = 0; dx < 3; ++dx) {
                    bf16x8 a = fr[(ii + dy) % 3][dx];
                    acc[0] = __builtin_amdgcn_mfma_f32_16x16x32_bf16(
                        bw[0][dy * 3 + dx], a, acc[0], 0, 0, 0);
                    acc[1] = __builtin_amdgcn_mfma_f32_16x16x32_bf16(
                        bw[1][dy * 3 + dx], a, acc[1], 0, 0, 0);
                }

            int gy = y0 + myb + ii;
            int gxx = x0 + tx * 16 + col;
            if (gy < H_ && gxx < W_) {
                size_t pxo = ((size_t)b * HW_ + (size_t)gy * W_ + gxx) * 24;
                uint2 st0;
                st0.x = packbf(acc[0].x + bias_r[0][0], acc[0].y + bias_r[0][1]);
                st0.y = packbf(acc[0].z + bias_r[0][2], acc[0].w + bias_r[0][3]);
                *(uint2*)&out[pxo + kg * 4] = st0;  // ch 0-15: c5|c10
                if (kg < 2) {
                    uint2 st1;
                    st1.x = packbf(acc[1].x + bias_r[1][0], acc[1].y + bias_r[1][1]);
                    st1.y = packbf(acc[1].z + bias_r[1][2], acc[1].w + bias_r[1][3]);
                    *(uint2*)&out[pxo + 16 + kg * 4] = st1;  // ch 16-23: c15
                }
            }
        }
    }
}

// ---------------------------------------------------------------------------
// Pools, NHWC. p5 from x; p10/p15 from p5 (hierarchical).
// ---------------------------------------------------------------------------
__global__ __launch_bounds__(256) void pool5_k(const unsigned short* __restrict__ x,
                                               unsigned short* __restrict__ p5,
                                               int n)
{
    int idx = blockIdx.x * 256 + threadIdx.x;
    if (idx >= n) return;
    int b = idx / 3600;
    int rem = idx - b * 3600;
    int i = rem / 60, j = rem - i * 60;
    const unsigned short* src =
        x + ((size_t)b * HW_ + (size_t)(i * 5) * W_ + j * 5) * 8;
    float ss[8] = {0, 0, 0, 0, 0, 0, 0, 0};
#pragma unroll
    for (int r = 0; r < 5; ++r)
#pragma unroll
        for (int c = 0; c < 5; ++c) {
            u16x8 v = *(const u16x8*)&src[((size_t)r * W_ + c) * 8];
#pragma unroll
            for (int k = 0; k < 8; ++k) ss[k] += b2f(v[k]);
        }
    uint4 st;
    st.x = packbf(ss[0] * 0.04f, ss[1] * 0.04f);
    st.y = packbf(ss[2] * 0.04f, ss[3] * 0.04f);
    st.z = packbf(ss[4] * 0.04f, ss[5] * 0.04f);
    st.w = packbf(ss[6] * 0.04f, ss[7] * 0.04f);
    *(uint4*)&p5[(size_t)idx * 8] = st;
}

template <int R, int OD>
__device__ __forceinline__ void poolr_body(const unsigned short* __restrict__ p5,
                                           unsigned short* __restrict__ po, int idx)
{
    int b = idx / (OD * OD);
    int rem = idx - b * OD * OD;
    int i = rem / OD, j = rem - i * OD;
    const unsigned short* src =
        p5 + ((size_t)b * 3600 + (size_t)(i * R) * 60 + j * R) * 8;
    float ss[8] = {0, 0, 0, 0, 0, 0, 0, 0};
    const float inv = 1.f / (R * R);
#pragma unroll
    for (int r = 0; r < R; ++r)
#pragma unroll
        for (int c = 0; c < R; ++c) {
            u16x8 v = *(const u16x8*)&src[((size_t)r * 60 + c) * 8];
#pragma unroll
            for (int k = 0; k < 8; ++k) ss[k] += b2f(v[k]);
        }
    uint4 st;
    st.x = packbf(ss[0] * inv, ss[1] * inv);
    st.y = packbf(ss[2] * inv, ss[3] * inv);
    st.z = packbf(ss[4] * inv, ss[5] * inv);
    st.w = packbf(ss[6] * inv, ss[7] * inv);
    *(uint4*)&po[(size_t)idx * 8] = st;
}

__global__ __launch_bounds__(256) void poolrs_k(const unsigned short* __restrict__ p5,
                                                unsigned short* __restrict__ p10,
                                                unsigned short* __restrict__ p15,
                                                int n10, int n15)
{
    int idx = blockIdx.x * 256 + threadIdx.x;
    if (idx < n10) {
        poolr_body<2, 30>(p5, p10, idx);
    } else {
        idx -= n10;
        if (idx < n15) poolr_body<3, 20>(p5, p15, idx);
    }
}

// ---------------------------------------------------------------------------
// Stage A: collapse NPART block-partials to 64 rows (parallel, coalesced).
// ---------------------------------------------------------------------------
__global__ __launch_bounds__(256) void reduce_parts_k(
    const float2* __restrict__ parts, float2* __restrict__ parts2)
{
    int k = blockIdx.x;
    int tid = threadIdx.x;
    int c = tid & 7, j = tid >> 3;  // j in 0..31
    float s = 0.f, s2 = 0.f;
    for (int r = j; r < NPB; r += 32) {
        float2 p = parts[((size_t)k * NPB + r) * 8 + c];
        s += p.x;
        s2 += p.y;
    }
    __shared__ float2 red[256];
    red[tid] = make_float2(s, s2);
    __syncthreads();
    if (tid < 8) {
        float a = 0.f, b = 0.f;
        for (int q = 0; q < 32; ++q) {
            float2 p = red[q * 8 + tid];
            a += p.x;
            b += p.y;
        }
        parts2[(size_t)k * 8 + tid] = make_float2(a, b);
    }
}

// Stage B: reduce 64 rows, fold BN into conv11 weights; wfold[t*8+ci], [72]=bias.
__global__ __launch_bounds__(256) void stats_fold_k(
    const float2* __restrict__ parts2, const float* __restrict__ bn_w,
    const float* __restrict__ bn_b, const float* __restrict__ w11,
    const float* __restrict__ b11, float* __restrict__ wfold)
{
    __shared__ float sc[8], tc[8];
    __shared__ float2 acc8[8];
    int tid = threadIdx.x;
    int c = tid >> 5, sl = tid & 31;
    float s = 0.f, s2 = 0.f;
    for (int i = sl; i < 64; i += 32) {
        float2 p = parts2[(size_t)i * 8 + c];
        s += p.x;
        s2 += p.y;
    }
#pragma unroll
    for (int off = 16; off > 0; off >>= 1) {
        s += __shfl_down(s, off, 32);
        s2 += __shfl_down(s2, off, 32);
    }
    if (sl == 0) acc8[c] = make_float2(s, s2);
    __syncthreads();
    if (tid < 8) {
        double ds = acc8[tid].x, ds2 = acc8[tid].y;
        double N = (double)NBATCH * HW_;
        double mean = ds / N;
        double var = ds2 / N - mean * mean;
        float rstd = (float)(1.0 / sqrt(var + 1e-5));
        float scv = bn_w[tid] * rstd;
        sc[tid] = scv;
        tc[tid] = bn_b[tid] - (float)mean * scv;
    }
    __syncthreads();
    if (tid < 72) {
        int t = tid >> 3, ci = tid & 7;
        wfold[tid] = w11[ci * 9 + t] * sc[ci];
    }
    if (tid == 72) {
        float a = b11[0];
        for (int i = 0; i < 72; ++i) a += w11[i] * tc[i / 9];
        wfold[72] = a;
    }
}

// ---------------------------------------------------------------------------
// Final: att = sigmoid(conv 8->1 over NHWC gated), blend with im (NCHW fp32).
// ---------------------------------------------------------------------------
__global__ __launch_bounds__(256) void final_k(
    const unsigned short* __restrict__ gated, const float* __restrict__ wf,
    const float* __restrict__ im, const float* __restrict__ gamma,
    float* __restrict__ out)
{
    __shared__ __align__(16) unsigned short s_g[1156 * 8];
    __shared__ float s_w[80];

    int b = blockIdx.z;
    int x0 = blockIdx.x * 32, y0 = blockIdx.y * 32;
    int tid = threadIdx.x;
    bool interior = (x0 >= 1) && (x0 + 32 < W_) && (y0 >= 1) && (y0 + 32 < H_);

    if (tid < 73) s_w[tid] = wf[tid];

    const unsigned short* gb = gated + (size_t)b * HW_ * 8;
    if (interior) {
        const unsigned short* gb0 = gb + ((size_t)(y0 - 1) * W_ + (x0 - 1)) * 8;
        for (int e = tid; e < 1156; e += 256) {
            int y = e / 34;
            u16x8 v = *(const u16x8*)&gb0[(size_t)(e + y * 266) * 8];
            *(u16x8*)&s_g[e * 8] = v;
        }
    } else {
        for (int e = tid; e < 1156; e += 256) {
            int y = e / 34, x = e - y * 34;
            int gy = y0 + y - 1, gx = x0 + x - 1;
            u16x8 v = {0, 0, 0, 0, 0, 0, 0, 0};
            if (gy >= 0 && gy < H_ && gx >= 0 && gx < W_)
                v = *(const u16x8*)&gb[((size_t)gy * W_ + gx) * 8];
            *(u16x8*)&s_g[e * 8] = v;
        }
    }
    __syncthreads();

    int qx = (tid & 15) * 2, qy = (tid >> 4) * 2;
    float f[4];
    float gm = *gamma;
#pragma unroll
    for (int p = 0; p < 4; ++p) {
        int ly = qy + (p >> 1), lx = qx + (p & 1);
        float acc = s_w[72];
#pragma unroll
        for (int t = 0; t < 9; ++t) {
            u16x8 n = *(const u16x8*)&s_g[((ly + t / 3) * 34 + lx + t % 3) * 8];
#pragma unroll
            for (int ci = 0; ci < 8; ++ci) acc += b2f(n[ci]) * s_w[t * 8 + ci];
        }
        f[p] = (1.f - gm) + gm * sigm(acc);
    }

    int px = x0 + qx, py = y0 + qy;
    if (px < W_) {
#pragma unroll
        for (int ch = 0; ch < 3; ++ch) {
            const float* imb = im + ((size_t)b * 3 + ch) * HW_;
            float* ob = out + ((size_t)b * 3 + ch) * HW_;
#pragma unroll
            for (int pr = 0; pr < 2; ++pr) {
                if (py + pr < H_) {
                    float2 iv = *(const float2*)&imb[(size_t)(py + pr) * W_ + px];
                    float2 ov;
                    ov.x = iv.x * f[pr * 2 + 0];
                    ov.y = iv.y * f[pr * 2 + 1];
                    *(float2*)&ob[(size_t)(py + pr) * W_ + px] = ov;
                }
            }
        }
    }
}

// ---------------------------------------------------------------------------

extern "C" void kernel_launch(void* const* d_in, const int* in_sizes, int n_in,
                              void* d_out, int out_size, void* d_ws,
                              size_t ws_size, hipStream_t stream)
{
    (void)in_sizes; (void)n_in; (void)out_size;

    const float* im  = (const float*)d_in[0];
    const float* w1  = (const float*)d_in[1];
    const float* b1  = (const float*)d_in[2];
    const float* w2  = (const float*)d_in[3];
    const float* b2  = (const float*)d_in[4];
    const float* w3  = (const float*)d_in[5];
    const float* b3  = (const float*)d_in[6];
    const float* w4  = (const float*)d_in[7];
    const float* b4  = (const float*)d_in[8];
    const float* w5  = (const float*)d_in[9];
    const float* b5  = (const float*)d_in[10];
    const float* wc5 = (const float*)d_in[11];
    const float* bc5 = (const float*)d_in[12];
    const float* wc10= (const float*)d_in[13];
    const float* bc10= (const float*)d_in[14];
    const float* wc15= (const float*)d_in[15];
    const float* bc15= (const float*)d_in[16];
    const float* wg  = (const float*)d_in[17];
    const float* bg  = (const float*)d_in[18];
    const float* wm  = (const float*)d_in[19];
    const float* bm  = (const float*)d_in[20];
    const float* bnw = (const float*)d_in[21];
    const float* bnb = (const float*)d_in[22];
    const float* w11 = (const float*)d_in[23];
    const float* b11 = (const float*)d_in[24];
    const float* gam = (const float*)d_in[25];
    float* out = (float*)d_out;

    // ---- workspace plan (chunked batch; deterministic in ws_size) ----------
    const size_t GATED_B = 46080000;
    const size_t PER_IMG = 1440000 + 2880000 + 5760000 + 57600 + 14400 + 6656;
    const size_t MISC    = 1048576;
    int c = 32;
    while (c > 1 && GATED_B + MISC + (size_t)c * PER_IMG + 2048 > ws_size)
        c >>= 1;

    char* p = (char*)d_ws;
    auto take = [&](size_t bytes) {
        char* r = p;
        p += (bytes + 255) & ~(size_t)255;
        return r;
    };
    unsigned short* GATED = (unsigned short*)take(GATED_B);
    unsigned short* A   = (unsigned short*)take((size_t)c * 1440000);
    unsigned short* Bb  = (unsigned short*)take((size_t)c * 2880000);
    unsigned short* C   = (unsigned short*)take((size_t)c * 5760000);
    unsigned short* P5  = (unsigned short*)take((size_t)c * 57600);
    unsigned short* P10 = (unsigned short*)take((size_t)c * 14400);
    unsigned short* P15 = (unsigned short*)take((size_t)c * 6656);
    float2* parts  = (float2*)take((size_t)NPART * 8 * sizeof(float2));
    float2* parts2 = (float2*)take(64 * 8 * sizeof(float2));
    float*  wfold  = (float*)take(512);
    unsigned short* WP = (unsigned short*)take(65536);

    unsigned short* PK2 = WP;            // conv2: 3 steps
    unsigned short* PK3 = WP + 2048;     // conv3: 5x2
    unsigned short* PK4 = WP + 8192;     // conv4: 9
    unsigned short* PK5 = WP + 13312;    // conv5: 5
    unsigned short* PKc = WP + 16384;    // convc composite: 9x2
    unsigned short* PKg = WP + 25600;    // gated: 9
    unsigned short* PK1 = WP + 30720;    // conv1: 3

    dim3 blk(256);

    pack_all_k<<<dim3(7), blk, 0, stream>>>(w1, w2, w3, w4, w5, wc5, wc10, wc15,
                                            wg, wm, WP);

    for (int b0 = 0; b0 < NBATCH; b0 += c) {
        dim3 g32(10, 10, c);   // TH=32 kernels
        dim3 g16(10, 19, c);   // TH=16 kernels
        const float* imc = im + (size_t)b0 * 3 * HW_;

        mfconv_k<8, 8, 8, 1, 3, 32><<<g32, blk, 0, stream>>>(
            (const unsigned short*)imc, PK1, b1, nullptr, A, 8, 0, nullptr, 0);
        mfconv_k<8, 8, 16, 1, 0, 32><<<g32, blk, 0, stream>>>(
            A, PK2, b2, nullptr, Bb, 16, 0, nullptr, 0);
        mfconv_k<16, 16, 32, 2, 0, 32><<<g32, blk, 0, stream>>>(
            Bb, PK3, b3, nullptr, C, 32, 0, nullptr, 0);
        mfconv_k<32, 32, 16, 1, 0, 16><<<g16, blk, 0, stream>>>(
            C, PK4, b4, nullptr, Bb, 16, 0, nullptr, 0);
        mfconv_k<16, 16, 8, 1, 0, 32><<<g32, blk, 0, stream>>>(
            Bb, PK5, b5, nullptr, A, 8, 0, nullptr, 0);

        int n5 = c * 3600, n10 = c * 900, n15 = c * 400;
        pool5_k<<<dim3((n5 + 255) / 256), blk, 0, stream>>>(A, P5, n5);
        poolrs_k<<<dim3((n10 + n15 + 255) / 256), blk, 0, stream>>>(P5, P10, P15,
                                                                    n10, n15);

        convc3_k<<<g16, blk, 0, stream>>>(A, P5, P10, P15, PKc, bc5, bc10, bc15, C);

        mfconv_k<24, 32, 16, 1, 2, 16><<<g16, blk, 0, stream>>>(
            C, PKg, bg, bm, GATED + (size_t)b0 * HW_ * 8, 8, 0, parts, b0);
    }

    reduce_parts_k<<<dim3(64), blk, 0, stream>>>(parts, parts2);
    stats_fold_k<<<dim3(1), blk, 0, stream>>>(parts2, bnw, bnb, w11, b11, wfold);
    final_k<<<dim3(10, 10, NBATCH), blk, 0, stream>>>(GATED, wfold, im, gam,
                                                      out);
}

// Round 13
// 413.099 us; speedup vs baseline: 1.0861x; 1.0146x over previous
//
#include <hip/hip_runtime.h>
#include <hip/hip_bf16.h>
#include <math.h>

typedef __hip_bfloat16 bf16;
typedef __attribute__((ext_vector_type(8))) __bf16 bf16x8;
typedef __attribute__((ext_vector_type(8))) unsigned short u16x8;
typedef __attribute__((ext_vector_type(4))) float f32x4;

#define H_ 300
#define W_ 300
#define HW_ 90000
#define NBATCH 32
#define NPART (NBATCH * 190)   // gated BN partials: one per gated (image,tile)
#define NPB 95                 // partial rows per reduce_parts block (6080/64)

__device__ __forceinline__ float b2f(unsigned short u) {
    return __uint_as_float((unsigned int)u << 16);
}
__device__ __forceinline__ unsigned short f2u(float v) {
    bf16 b = __float2bfloat16(v);
    return *reinterpret_cast<unsigned short*>(&b);
}
__device__ __forceinline__ float sigm(float x) { return 1.f / (1.f + __expf(-x)); }
// HW packed fp32->bf16 pair (RNE), 1 instr vs ~10 for the manual sequence.
__device__ __forceinline__ unsigned int packbf(float a, float b) {
    unsigned int r;
    asm("v_cvt_pk_bf16_f32 %0, %1, %2" : "=v"(r) : "v"(a), "v"(b));
    return r;
}
// Async global->LDS DMA, 16B per lane. LDS dest = wave-uniform base + lane*16;
// global src is per-lane. vmcnt drained by the compiler before s_barrier.
__device__ __forceinline__ void async_cp16(void* lds_base, const void* g) {
    __builtin_amdgcn_global_load_lds(
        (const __attribute__((address_space(1))) unsigned int*)g,
        (__attribute__((address_space(3))) unsigned int*)lds_base, 16, 0, 0);
}

// ---------------------------------------------------------------------------
// All weight prepacks in ONE launch (7 blocks). Fragment order: A operand,
// row = lane&15 = co, k = (lane>>4)*8+j; pack[step][g][lane][j] bf16.
// Block 4 is the convc composite (see convc3_k).
// ---------------------------------------------------------------------------
__global__ void pack_all_k(
    const float* __restrict__ w1, const float* __restrict__ w2,
    const float* __restrict__ w3, const float* __restrict__ w4,
    const float* __restrict__ w5, const float* __restrict__ wc5,
    const float* __restrict__ wc10, const float* __restrict__ wc15,
    const float* __restrict__ wg, const float* __restrict__ wm,
    unsigned short* __restrict__ WP)
{
    const float *a = nullptr, *bsec = nullptr;
    int cs = 999, CO = 0, CI = 0, CP = 8, NS = 3, NG = 1, off = 0, special = 0;
    switch (blockIdx.x) {
        case 0: a = w2;  CO = 16; CI = 8;  CP = 8;  NS = 3; off = 0;     break;
        case 1: a = w3;  CO = 32; CI = 16; CP = 16; NS = 5; NG = 2; off = 2048;  break;
        case 2: a = w4;  CO = 16; CI = 32; CP = 32; NS = 9; off = 8192;  break;
        case 3: a = w5;  CO = 8;  CI = 16; CP = 16; NS = 5; off = 13312; break;
        case 4: special = 1; CO = 32; CI = 32; CP = 32; NS = 9; NG = 2;
                off = 16384; break;
        case 5: a = wg; bsec = wm; cs = 8; CO = 16; CI = 24; CP = 32; NS = 9;
                off = 25600; break;
        case 6: a = w1;  CO = 8;  CI = 3;  CP = 8;  NS = 3; off = 30720; break;
    }
    unsigned short* outp = WP + off;
    int TPK = 32 / CP;
    int total = NS * NG * 512;
    for (int idx = threadIdx.x; idx < total; idx += 256) {
        int j = idx & 7;
        int lane = (idx >> 3) & 63;
        int g = (idx >> 9) % NG;
        int s = idx / (512 * NG);
        int col = lane & 15, kg = lane >> 4;
        int kk = kg * 8 + j;
        int tt = kk / CP, ci = kk % CP;
        int tap = s * TPK + tt;
        float v = 0.f;
        if (special) {
            int o = ci >> 3, c8 = ci & 7;
            int convid = (g == 0) ? (col < 8 ? 0 : 1) : (col < 8 ? 2 : -1);
            if (tap < 9 && convid >= 0) {
                const float* wc = (convid == 0) ? wc5 : (convid == 1) ? wc10 : wc15;
                int colc = col & 7;
                if (o == 0) v = wc[(colc * 16 + c8) * 9 + tap];
                else if (o == convid + 1) v = wc[(colc * 16 + 8 + c8) * 9 + tap];
            }
        } else {
            int co = g * 16 + col;
            if (tap < 9 && ci < CI && co < CO)
                v = (co >= cs) ? bsec[((co - cs) * CI + ci) * 9 + tap]
                               : a[(co * CI + ci) * 9 + tap];
        }
        outp[idx] = f2u(v);
    }
}

// ---------------------------------------------------------------------------
// Fused conv1+conv2: one 32x32 output tile of x2.
// Phase A: stage im (fp32 NCHW, 3ch) 36x36 halo^2 region -> bf16 LDS s_im.
// Phase B: conv1 on the 34x34 halo region -> s_x1 (zeros at global OOB).
//   3 col-groups of 16 (cols 34..47 garbage — confined to discarded output
//   columns because MFMA pixel-columns are lane-local).
// Phase C: conv2 standard loop reading s_x1, writing x2 (16ch NHWC) global.
// ---------------------------------------------------------------------------
__global__ __launch_bounds__(256) void fused12_k(
    const float* __restrict__ im, const unsigned short* __restrict__ wp1,
    const float* __restrict__ b1, const unsigned short* __restrict__ wp2,
    const float* __restrict__ b2, unsigned short* __restrict__ out)
{
    __shared__ __align__(16) unsigned short s_im[1296 * 8];   // 36x36
    __shared__ __align__(16) unsigned short s_x1[1156 * 8];   // 34x34

    int b = blockIdx.z;
    int x0 = blockIdx.x * 32, y0 = blockIdx.y * 32;
    int tid = threadIdx.x;
    int lane = tid & 63, wv = tid >> 6;
    int col = lane & 15, kg = lane >> 4;

    // ---- Phase A: stage im ----
    const float* sf = im + (size_t)b * 3 * HW_;
    bool interior = (x0 >= 2) && (x0 + 34 < W_) && (y0 >= 2) && (y0 + 34 < H_);
    if (interior) {
        const float* sf0 = sf + (size_t)(y0 - 2) * W_ + (x0 - 2);
        for (int e = tid; e < 1296; e += 256) {
            int y = e / 36;
            size_t o = (size_t)e + (size_t)y * 264;   // y*300 + x = e + y*(300-36)
            u16x8 v = {0, 0, 0, 0, 0, 0, 0, 0};
            v[0] = f2u(sf0[o]);
            v[1] = f2u(sf0[HW_ + o]);
            v[2] = f2u(sf0[2 * HW_ + o]);
            *(u16x8*)&s_im[e * 8] = v;
        }
    } else {
        for (int e = tid; e < 1296; e += 256) {
            int y = e / 36, x = e - y * 36;
            int gy = y0 + y - 2, gx = x0 + x - 2;
            u16x8 v = {0, 0, 0, 0, 0, 0, 0, 0};
            if (gy >= 0 && gy < H_ && gx >= 0 && gx < W_) {
                size_t o = (size_t)gy * W_ + gx;
                v[0] = f2u(sf[o]);
                v[1] = f2u(sf[HW_ + o]);
                v[2] = f2u(sf[2 * HW_ + o]);
            }
            *(u16x8*)&s_im[e * 8] = v;
        }
    }

    // ---- weights for both convs (loaded pre-barrier) ----
    bf16x8 bw1[3], bw2[3];
#pragma unroll
    for (int s = 0; s < 3; ++s) {
        bw1[s] = *(const bf16x8*)&wp1[(s * 64 + lane) * 8];
        bw2[s] = *(const bf16x8*)&wp2[(s * 64 + lane) * 8];
    }

    int offs1[3], offs2[3];
#pragma unroll
    for (int s = 0; s < 3; ++s) {
        int t = s * 4 + kg;
        if (t > 8) t = 8;  // weights zero there
        offs1[s] = ((t / 3) * 36 + (t % 3)) * 8;
        offs2[s] = ((t / 3) * 34 + (t % 3)) * 8;
    }

    float b1r[4], b2r[4];
#pragma unroll
    for (int r = 0; r < 4; ++r) {
        int co1 = kg * 4 + r;
        b1r[r] = (co1 < 8) ? b1[co1] : 0.f;
        b2r[r] = b2[kg * 4 + r];   // COUT=16: kg*4+r in 0..15
    }

    __syncthreads();

    // ---- Phase B: conv1 -> s_x1 (34x34, origin global (y0-1, x0-1)) ----
    for (int r = wv; r < 34; r += 4) {
#pragma unroll
        for (int cg = 0; cg < 3; ++cg) {
            int base = (r * 36 + cg * 16 + col) * 8;
            f32x4 acc = {0.f, 0.f, 0.f, 0.f};
#pragma unroll
            for (int s = 0; s < 3; ++s) {
                bf16x8 a = *(const bf16x8*)&s_im[base + offs1[s]];
                acc = __builtin_amdgcn_mfma_f32_16x16x32_bf16(bw1[s], a, acc, 0, 0, 0);
            }
            int c = cg * 16 + col;
            if (kg < 2 && c < 34) {
                int gy = y0 - 1 + r, gx = x0 - 1 + c;
                bool ok = (gy >= 0) && (gy < H_) && (gx >= 0) && (gx < W_);
                float o0 = ok ? acc.x + b1r[0] : 0.f;
                float o1 = ok ? acc.y + b1r[1] : 0.f;
                float o2 = ok ? acc.z + b1r[2] : 0.f;
                float o3 = ok ? acc.w + b1r[3] : 0.f;
                uint2 st;
                st.x = packbf(o0, o1);
                st.y = packbf(o2, o3);
                *(uint2*)&s_x1[(r * 34 + c) * 8 + kg * 4] = st;
            }
        }
    }
    __syncthreads();

    // ---- Phase C: conv2 from s_x1 -> x2 global (16ch NHWC) ----
#pragma unroll
    for (int i = 0; i < 16; ++i) {
        int m = wv * 16 + i;
        int my = m >> 1, tx = m & 1;
        int gy = y0 + my;
        if (gy >= H_) continue;  // wave-uniform
        int base = (my * 34 + tx * 16 + col) * 8;

        f32x4 acc = {0.f, 0.f, 0.f, 0.f};
#pragma unroll
        for (int s = 0; s < 3; ++s) {
            bf16x8 a = *(const bf16x8*)&s_x1[base + offs2[s]];
            acc = __builtin_amdgcn_mfma_f32_16x16x32_bf16(bw2[s], a, acc, 0, 0, 0);
        }

        int gxx = x0 + tx * 16 + col;
        if (gxx < W_) {
            uint2 st;
            st.x = packbf(acc.x + b2r[0], acc.y + b2r[1]);
            st.y = packbf(acc.z + b2r[2], acc.w + b2r[3]);
            *(uint2*)&out[((size_t)b * HW_ + (size_t)gy * W_ + gxx) * 16 +
                          kg * 4] = st;
        }
    }
}

// ---------------------------------------------------------------------------
// MFMA implicit-GEMM 3x3 conv, NHWC in/out. Tile 32xTH px, 4 waves.
// Octet-planar LDS s_in[oct][(TH+2)*34 px][8ch]. OCT==4 uses a ROW-CACHED
// inner loop (3 new ds_reads/row instead of 9). INTERIOR staging uses
// global_load_lds width-16 DMA. Boundary blocks use the register path.
// MODE 0: plain. MODE 2: gated (rows 0-7 g, 8-15 m; out = g*sigm(m)) and
// fused BN partial stats (one float2x8 per (image,tile)).
// ---------------------------------------------------------------------------
template <int CIN, int CINP, int COUT, int NGI, int MODE, int TH>
__global__ __launch_bounds__(256) void mfconv_k(
    const unsigned short* __restrict__ src,
    const unsigned short* __restrict__ wpack,
    const float* __restrict__ bias0, const float* __restrict__ bias1,
    unsigned short* __restrict__ out, int co_total, int co_off,
    float2* __restrict__ bnp, int img_base)
{
    constexpr int TPK = 32 / CINP;
    constexpr int NSTEP = (9 + TPK - 1) / TPK;
    constexpr int OCT = CINP / 8;
    constexpr int NPX = (TH + 2) * 34;
    constexpr int STRIDE = 256 / OCT;

    __shared__ __align__(16) unsigned short s_in[OCT * NPX * 8];

    int b = blockIdx.z;
    int x0 = blockIdx.x * 32, y0 = blockIdx.y * TH;
    int tid = threadIdx.x;
    int lane = tid & 63, wv = tid >> 6;
    bool interior = (x0 >= 1) && (x0 + 32 < W_) && (y0 >= 1) && (y0 + TH < H_);

    int oct = (OCT == 1) ? 0 : (wv % OCT);
    int phase = (OCT == 4) ? 0 : (wv / OCT);
    bool voct = (CIN == CINP) || (oct * 8 < CIN);

    // ---- staging ----
    {
        const unsigned short* sb = src + (size_t)b * CIN * HW_;
        if (interior) {
            if (voct) {
                const unsigned short* sb0 =
                    sb + ((size_t)(y0 - 1) * W_ + (x0 - 1)) * CIN + oct * 8;
#pragma unroll
                for (int pxb = 0; pxb < NPX; pxb += STRIDE) {
                    int base = phase * 64 + pxb;
                    if (base >= NPX) break;
                    int px = base + lane;
                    if (px < NPX) {
                        int y = px / 34;
                        async_cp16(&s_in[(oct * NPX + base) * 8],
                                   &sb0[(size_t)(px + y * 266) * CIN]);
                    }
                }
            } else {
                u16x8 z8 = {0, 0, 0, 0, 0, 0, 0, 0};
                for (int px = lane + phase * 64; px < NPX; px += STRIDE)
                    *(u16x8*)&s_in[(oct * NPX + px) * 8] = z8;
            }
        } else {
            for (int px = lane + phase * 64; px < NPX; px += STRIDE) {
                int y = px / 34, x = px - y * 34;
                int gy = y0 + y - 1, gx = x0 + x - 1;
                u16x8 v = {0, 0, 0, 0, 0, 0, 0, 0};
                if (gy >= 0 && gy < H_ && gx >= 0 && gx < W_ && voct)
                    v = *(const u16x8*)&sb[((size_t)gy * W_ + gx) * CIN + oct * 8];
                *(u16x8*)&s_in[(oct * NPX + px) * 8] = v;
            }
        }
    }

    // ---- weight fragments (NGI groups) ----
    bf16x8 bw[NGI][NSTEP];
#pragma unroll
    for (int gi = 0; gi < NGI; ++gi)
#pragma unroll
        for (int s = 0; s < NSTEP; ++s)
            bw[gi][s] = *(const bf16x8*)&wpack[((s * NGI + gi) * 64 + lane) * 8];

    int col = lane & 15, kg = lane >> 4;

    float bias_r[NGI][4];
#pragma unroll
    for (int gi = 0; gi < NGI; ++gi)
#pragma unroll
        for (int r = 0; r < 4; ++r) {
            if (MODE == 2)
                bias_r[0][r] = (kg < 2) ? bias0[kg * 4 + r] : bias1[(kg - 2) * 4 + r];
            else {
                int co_l = gi * 16 + kg * 4 + r;
                bias_r[gi][r] = (co_l < COUT) ? bias0[co_l] : 0.f;
            }
        }

    float bs[4] = {0.f, 0.f, 0.f, 0.f}, bs2[4] = {0.f, 0.f, 0.f, 0.f};

    __syncthreads();

    if constexpr (OCT == 4) {
        // ---- row-cached inner loop (TPK==1: step s == tap s) ----
        int myb = wv * (TH / 4);
#pragma unroll
        for (int tx = 0; tx < 2; ++tx) {
            int pbase = kg * NPX + tx * 16 + col;
            bf16x8 fr[3][3];
#pragma unroll
            for (int r = 0; r < 2; ++r)
#pragma unroll
                for (int dx = 0; dx < 3; ++dx)
                    fr[r][dx] =
                        *(const bf16x8*)&s_in[(pbase + (myb + r) * 34 + dx) * 8];
#pragma unroll
            for (int ii = 0; ii < TH / 4; ++ii) {
#pragma unroll
                for (int dx = 0; dx < 3; ++dx)
                    fr[(ii + 2) % 3][dx] =
                        *(const bf16x8*)&s_in[(pbase + (myb + ii + 2) * 34 + dx) * 8];

                f32x4 acc[NGI];
#pragma unroll
                for (int gi = 0; gi < NGI; ++gi) acc[gi] = {0.f, 0.f, 0.f, 0.f};
#pragma unroll
                for (int dy = 0; dy < 3; ++dy)
#pragma unroll
                    for (int dx = 0; dx < 3; ++dx) {
                        bf16x8 a = fr[(ii + dy) % 3][dx];
#pragma unroll
                        for (int gi = 0; gi < NGI; ++gi)
                            acc[gi] = __builtin_amdgcn_mfma_f32_16x16x32_bf16(
                                bw[gi][dy * 3 + dx], a, acc[gi], 0, 0, 0);
                    }

                int gy = y0 + myb + ii;
                int gxx = x0 + tx * 16 + col;
                if (gy < H_) {
                    if (MODE == 2) {
                        float v0 = acc[0].x + bias_r[0][0];
                        float v1 = acc[0].y + bias_r[0][1];
                        float v2 = acc[0].z + bias_r[0][2];
                        float v3 = acc[0].w + bias_r[0][3];
                        float m0 = __shfl_xor(v0, 32), m1 = __shfl_xor(v1, 32);
                        float m2 = __shfl_xor(v2, 32), m3 = __shfl_xor(v3, 32);
                        if (kg < 2 && gxx < W_) {
                            float o0 = v0 * sigm(m0), o1 = v1 * sigm(m1);
                            float o2 = v2 * sigm(m2), o3 = v3 * sigm(m3);
                            uint2 st;
                            st.x = packbf(o0, o1);
                            st.y = packbf(o2, o3);
                            *(uint2*)&out[(((size_t)b * HW_ + (size_t)gy * W_ +
                                            gxx) * 8) + kg * 4] = st;
                            bs[0] += o0; bs2[0] += o0 * o0;
                            bs[1] += o1; bs2[1] += o1 * o1;
                            bs[2] += o2; bs2[2] += o2 * o2;
                            bs[3] += o3; bs2[3] += o3 * o3;
                        }
                    } else {
#pragma unroll
                        for (int gi = 0; gi < NGI; ++gi) {
                            int co_g = gi * 16 + kg * 4;
                            if (co_g < COUT && gxx < W_) {
                                uint2 st;
                                st.x = packbf(acc[gi].x + bias_r[gi][0],
                                              acc[gi].y + bias_r[gi][1]);
                                st.y = packbf(acc[gi].z + bias_r[gi][2],
                                              acc[gi].w + bias_r[gi][3]);
                                *(uint2*)&out[((size_t)b * HW_ +
                                               (size_t)gy * W_ + gxx) *
                                                  co_total + co_off + co_g] = st;
                            }
                        }
                    }
                }
            }
        }
    } else {
        // ---- generic loop for OCT<=2 ----
        int offs[NSTEP];
#pragma unroll
        for (int s = 0; s < NSTEP; ++s) {
            int t = s * TPK + kg / OCT;
            if (t > 8) t = 8;  // padded taps: weights are zero there
            offs[s] = ((t / 3) * 34 + (t % 3)) * 8 + (kg % OCT) * (NPX * 8);
        }

#pragma unroll
        for (int i = 0; i < TH / 2; ++i) {
            int m = wv * (TH / 2) + i;
            int my = m >> 1, tx = m & 1;
            int gy = y0 + my;
            if (gy >= H_) continue;  // wave-uniform
            int base = (my * 34 + tx * 16 + col) * 8;

            f32x4 acc[NGI];
#pragma unroll
            for (int gi = 0; gi < NGI; ++gi) acc[gi] = {0.f, 0.f, 0.f, 0.f};
#pragma unroll
            for (int s = 0; s < NSTEP; ++s) {
                bf16x8 a = *(const bf16x8*)&s_in[base + offs[s]];
#pragma unroll
                for (int gi = 0; gi < NGI; ++gi)
                    acc[gi] = __builtin_amdgcn_mfma_f32_16x16x32_bf16(
                        bw[gi][s], a, acc[gi], 0, 0, 0);
            }

            int gxx = x0 + tx * 16 + col;
#pragma unroll
            for (int gi = 0; gi < NGI; ++gi) {
                int co_g = gi * 16 + kg * 4;
                if (co_g < COUT && gxx < W_) {
                    uint2 st;
                    st.x = packbf(acc[gi].x + bias_r[gi][0],
                                  acc[gi].y + bias_r[gi][1]);
                    st.y = packbf(acc[gi].z + bias_r[gi][2],
                                  acc[gi].w + bias_r[gi][3]);
                    *(uint2*)&out[((size_t)b * HW_ + (size_t)gy * W_ + gxx) *
                                      co_total + co_off + co_g] = st;
                }
            }
        }
    }

    // ---- fused BN partial stats (gated only): block-local, deterministic ----
    if constexpr (MODE == 2) {
#pragma unroll
        for (int off = 1; off < 16; off <<= 1) {
#pragma unroll
            for (int r = 0; r < 4; ++r) {
                bs[r] += __shfl_xor(bs[r], off);
                bs2[r] += __shfl_xor(bs2[r], off);
            }
        }
        __shared__ float bsum[4][8], bsq[4][8];
        if (lane == 0) {
#pragma unroll
            for (int r = 0; r < 4; ++r) { bsum[wv][r] = bs[r]; bsq[wv][r] = bs2[r]; }
        }
        if (lane == 16) {
#pragma unroll
            for (int r = 0; r < 4; ++r) {
                bsum[wv][4 + r] = bs[r];
                bsq[wv][4 + r] = bs2[r];
            }
        }
        __syncthreads();
        if (tid < 8) {
            float s = 0.f, s2 = 0.f;
#pragma unroll
            for (int w = 0; w < 4; ++w) { s += bsum[w][tid]; s2 += bsq[w][tid]; }
            int bIdx = (img_base + b) * 190 + blockIdx.y * 10 + blockIdx.x;
            bnp[(size_t)bIdx * 8 + tid] = make_float2(s, s2);
        }
    }
}

// ---------------------------------------------------------------------------
// Fused cK trio as ONE composite 32-ch conv (planes x|up5|up10|up15) with
// NGI=2 column groups ({c5,c10}, {c15}) and the row-cached inner loop.
// Interior x-plane staged via global_load_lds DMA; pool planes via registers.
// ---------------------------------------------------------------------------
__global__ __launch_bounds__(256) void convc3_k(
    const unsigned short* __restrict__ src,
    const unsigned short* __restrict__ p5, const unsigned short* __restrict__ p10,
    const unsigned short* __restrict__ p15,
    const unsigned short* __restrict__ wpack,
    const float* __restrict__ bc5, const float* __restrict__ bc10,
    const float* __restrict__ bc15, unsigned short* __restrict__ out)
{
    constexpr int TH = 16;
    constexpr int NPX = (TH + 2) * 34;
    __shared__ __align__(16) unsigned short s_in[4 * NPX * 8];

    int b = blockIdx.z;
    int x0 = blockIdx.x * 32, y0 = blockIdx.y * TH;
    int tid = threadIdx.x;
    int lane = tid & 63, wv = tid >> 6;
    bool interior = (x0 >= 1) && (x0 + 32 < W_) && (y0 >= 1) && (y0 + TH < H_);

    const unsigned short* sb = src + (size_t)b * 8 * HW_;
    const unsigned short* pb5 = p5 + (size_t)b * 8 * 3600;
    const unsigned short* pb10 = p10 + (size_t)b * 8 * 900;
    const unsigned short* pb15 = p15 + (size_t)b * 8 * 400;

    int oct = wv;  // wave-uniform plane
    if (interior) {
        if (oct == 0) {
            const unsigned short* sb0 =
                sb + ((size_t)(y0 - 1) * W_ + (x0 - 1)) * 8;
#pragma unroll
            for (int base = 0; base < NPX; base += 64) {
                int px = base + lane;
                if (px < NPX) {
                    int y = px / 34;
                    async_cp16(&s_in[(size_t)base * 8],
                               &sb0[(size_t)(px + y * 266) * 8]);
                }
            }
        } else {
            for (int px = lane; px < NPX; px += 64) {
                int y = px / 34, x = px - y * 34;
                int gy = y0 - 1 + y, gx = x0 - 1 + x;
                const unsigned short* pp =
                    (oct == 1) ? &pb5[((size_t)(gy / 5) * 60 + gx / 5) * 8]
                    : (oct == 2) ? &pb10[((size_t)(gy / 10) * 30 + gx / 10) * 8]
                                 : &pb15[((size_t)(gy / 15) * 20 + gx / 15) * 8];
                *(u16x8*)&s_in[(oct * NPX + px) * 8] = *(const u16x8*)pp;
            }
        }
    } else {
        for (int px = lane; px < NPX; px += 64) {
            int y = px / 34, x = px - y * 34;
            int gy = y0 + y - 1, gx = x0 + x - 1;
            u16x8 v = {0, 0, 0, 0, 0, 0, 0, 0};
            if (gy >= 0 && gy < H_ && gx >= 0 && gx < W_) {
                if (oct == 0)
                    v = *(const u16x8*)&sb[((size_t)gy * W_ + gx) * 8];
                else if (oct == 1)
                    v = *(const u16x8*)&pb5[((size_t)(gy / 5) * 60 + gx / 5) * 8];
                else if (oct == 2)
                    v = *(const u16x8*)&pb10[((size_t)(gy / 10) * 30 + gx / 10) * 8];
                else
                    v = *(const u16x8*)&pb15[((size_t)(gy / 15) * 20 + gx / 15) * 8];
            }
            *(u16x8*)&s_in[(oct * NPX + px) * 8] = v;
        }
    }

    bf16x8 bw[2][9];
#pragma unroll
    for (int g = 0; g < 2; ++g)
#pragma unroll
        for (int s = 0; s < 9; ++s)
            bw[g][s] = *(const bf16x8*)&wpack[((s * 2 + g) * 64 + lane) * 8];

    int col = lane & 15, kg = lane >> 4;
    float bias_r[2][4];
#pragma unroll
    for (int r = 0; r < 4; ++r) {
        bias_r[0][r] = (kg < 2) ? bc5[kg * 4 + r] : bc10[(kg - 2) * 4 + r];
        bias_r[1][r] = (kg < 2) ? bc15[kg * 4 + r] : 0.f;
    }

    __syncthreads();

    int myb = wv * (TH / 4);
#pragma unroll
    for (int tx = 0; tx < 2; ++tx) {
        int pbase = kg * NPX + tx * 16 + col;
        bf16x8 fr[3][3];
#pragma unroll
        for (int r = 0; r < 2; ++r)
#pragma unroll
            for (int dx = 0; dx < 3; ++dx)
                fr[r][dx] = *(const bf16x8*)&s_in[(pbase + (myb + r) * 34 + dx) * 8];
#pragma unroll
        for (int ii = 0; ii < TH / 4; ++ii) {
#pragma unroll
            for (int dx = 0; dx < 3; ++dx)
                fr[(ii + 2) % 3][dx] =
                    *(const bf16x8*)&s_in[(pbase + (myb + ii + 2) * 34 + dx) * 8];

            f32x4 acc[2];
            acc[0] = {0.f, 0.f, 0.f, 0.f};
            acc[1] = {0.f, 0.f, 0.f, 0.f};
#pragma unroll
            for (int dy = 0; dy < 3; ++dy)
#pragma unroll
                for (int dx = 0; dx < 3; ++dx) {
                    bf16x8 a = fr[(ii + dy) % 3][dx];
                    acc[0] = __builtin_amdgcn_mfma_f32_16x16x32_bf16(
                        bw[0][dy * 3 + dx], a, acc[0], 0, 0, 0);
                    acc[1] = __builtin_amdgcn_mfma_f32_16x16x32_bf16(
                        bw[1][dy * 3 + dx], a, acc[1], 0, 0, 0);
                }

            int gy = y0 + myb + ii;
            int gxx = x0 + tx * 16 + col;
            if (gy < H_ && gxx < W_) {
                size_t pxo = ((size_t)b * HW_ + (size_t)gy * W_ + gxx) * 24;
                uint2 st0;
                st0.x = packbf(acc[0].x + bias_r[0][0], acc[0].y + bias_r[0][1]);
                st0.y = packbf(acc[0].z + bias_r[0][2], acc[0].w + bias_r[0][3]);
                *(uint2*)&out[pxo + kg * 4] = st0;  // ch 0-15: c5|c10
                if (kg < 2) {
                    uint2 st1;
                    st1.x = packbf(acc[1].x + bias_r[1][0], acc[1].y + bias_r[1][1]);
                    st1.y = packbf(acc[1].z + bias_r[1][2], acc[1].w + bias_r[1][3]);
                    *(uint2*)&out[pxo + 16 + kg * 4] = st1;  // ch 16-23: c15
                }
            }
        }
    }
}

// ---------------------------------------------------------------------------
// Pools, NHWC. p5 from x; p10/p15 from p5 (hierarchical).
// ---------------------------------------------------------------------------
__global__ __launch_bounds__(256) void pool5_k(const unsigned short* __restrict__ x,
                                               unsigned short* __restrict__ p5,
                                               int n)
{
    int idx = blockIdx.x * 256 + threadIdx.x;
    if (idx >= n) return;
    int b = idx / 3600;
    int rem = idx - b * 3600;
    int i = rem / 60, j = rem - i * 60;
    const unsigned short* src =
        x + ((size_t)b * HW_ + (size_t)(i * 5) * W_ + j * 5) * 8;
    float ss[8] = {0, 0, 0, 0, 0, 0, 0, 0};
#pragma unroll
    for (int r = 0; r < 5; ++r)
#pragma unroll
        for (int c = 0; c < 5; ++c) {
            u16x8 v = *(const u16x8*)&src[((size_t)r * W_ + c) * 8];
#pragma unroll
            for (int k = 0; k < 8; ++k) ss[k] += b2f(v[k]);
        }
    uint4 st;
    st.x = packbf(ss[0] * 0.04f, ss[1] * 0.04f);
    st.y = packbf(ss[2] * 0.04f, ss[3] * 0.04f);
    st.z = packbf(ss[4] * 0.04f, ss[5] * 0.04f);
    st.w = packbf(ss[6] * 0.04f, ss[7] * 0.04f);
    *(uint4*)&p5[(size_t)idx * 8] = st;
}

template <int R, int OD>
__device__ __forceinline__ void poolr_body(const unsigned short* __restrict__ p5,
                                           unsigned short* __restrict__ po, int idx)
{
    int b = idx / (OD * OD);
    int rem = idx - b * OD * OD;
    int i = rem / OD, j = rem - i * OD;
    const unsigned short* src =
        p5 + ((size_t)b * 3600 + (size_t)(i * R) * 60 + j * R) * 8;
    float ss[8] = {0, 0, 0, 0, 0, 0, 0, 0};
    const float inv = 1.f / (R * R);
#pragma unroll
    for (int r = 0; r < R; ++r)
#pragma unroll
        for (int c = 0; c < R; ++c) {
            u16x8 v = *(const u16x8*)&src[((size_t)r * 60 + c) * 8];
#pragma unroll
            for (int k = 0; k < 8; ++k) ss[k] += b2f(v[k]);
        }
    uint4 st;
    st.x = packbf(ss[0] * inv, ss[1] * inv);
    st.y = packbf(ss[2] * inv, ss[3] * inv);
    st.z = packbf(ss[4] * inv, ss[5] * inv);
    st.w = packbf(ss[6] * inv, ss[7] * inv);
    *(uint4*)&po[(size_t)idx * 8] = st;
}

__global__ __launch_bounds__(256) void poolrs_k(const unsigned short* __restrict__ p5,
                                                unsigned short* __restrict__ p10,
                                                unsigned short* __restrict__ p15,
                                                int n10, int n15)
{
    int idx = blockIdx.x * 256 + threadIdx.x;
    if (idx < n10) {
        poolr_body<2, 30>(p5, p10, idx);
    } else {
        idx -= n10;
        if (idx < n15) poolr_body<3, 20>(p5, p15, idx);
    }
}

// ---------------------------------------------------------------------------
// Stage A: collapse NPART block-partials to 64 rows (parallel, coalesced).
// ---------------------------------------------------------------------------
__global__ __launch_bounds__(256) void reduce_parts_k(
    const float2* __restrict__ parts, float2* __restrict__ parts2)
{
    int k = blockIdx.x;
    int tid = threadIdx.x;
    int c = tid & 7, j = tid >> 3;  // j in 0..31
    float s = 0.f, s2 = 0.f;
    for (int r = j; r < NPB; r += 32) {
        float2 p = parts[((size_t)k * NPB + r) * 8 + c];
        s += p.x;
        s2 += p.y;
    }
    __shared__ float2 red[256];
    red[tid] = make_float2(s, s2);
    __syncthreads();
    if (tid < 8) {
        float a = 0.f, b = 0.f;
        for (int q = 0; q < 32; ++q) {
            float2 p = red[q * 8 + tid];
            a += p.x;
            b += p.y;
        }
        parts2[(size_t)k * 8 + tid] = make_float2(a, b);
    }
}

// Stage B: reduce 64 rows, fold BN into conv11 weights; wfold[t*8+ci], [72]=bias.
__global__ __launch_bounds__(256) void stats_fold_k(
    const float2* __restrict__ parts2, const float* __restrict__ bn_w,
    const float* __restrict__ bn_b, const float* __restrict__ w11,
    const float* __restrict__ b11, float* __restrict__ wfold)
{
    __shared__ float sc[8], tc[8];
    __shared__ float2 acc8[8];
    int tid = threadIdx.x;
    int c = tid >> 5, sl = tid & 31;
    float s = 0.f, s2 = 0.f;
    for (int i = sl; i < 64; i += 32) {
        float2 p = parts2[(size_t)i * 8 + c];
        s += p.x;
        s2 += p.y;
    }
#pragma unroll
    for (int off = 16; off > 0; off >>= 1) {
        s += __shfl_down(s, off, 32);
        s2 += __shfl_down(s2, off, 32);
    }
    if (sl == 0) acc8[c] = make_float2(s, s2);
    __syncthreads();
    if (tid < 8) {
        double ds = acc8[tid].x, ds2 = acc8[tid].y;
        double N = (double)NBATCH * HW_;
        double mean = ds / N;
        double var = ds2 / N - mean * mean;
        float rstd = (float)(1.0 / sqrt(var + 1e-5));
        float scv = bn_w[tid] * rstd;
        sc[tid] = scv;
        tc[tid] = bn_b[tid] - (float)mean * scv;
    }
    __syncthreads();
    if (tid < 72) {
        int t = tid >> 3, ci = tid & 7;
        wfold[tid] = w11[ci * 9 + t] * sc[ci];
    }
    if (tid == 72) {
        float a = b11[0];
        for (int i = 0; i < 72; ++i) a += w11[i] * tc[i / 9];
        wfold[72] = a;
    }
}

// ---------------------------------------------------------------------------
// Final: att = sigmoid(conv 8->1 over NHWC gated), blend with im (NCHW fp32).
// Interior staging via global_load_lds DMA.
// ---------------------------------------------------------------------------
__global__ __launch_bounds__(256) void final_k(
    const unsigned short* __restrict__ gated, const float* __restrict__ wf,
    const float* __restrict__ im, const float* __restrict__ gamma,
    float* __restrict__ out)
{
    __shared__ __align__(16) unsigned short s_g[1156 * 8];
    __shared__ float s_w[80];

    int b = blockIdx.z;
    int x0 = blockIdx.x * 32, y0 = blockIdx.y * 32;
    int tid = threadIdx.x;
    int lane = tid & 63, wv = tid >> 6;
    bool interior = (x0 >= 1) && (x0 + 32 < W_) && (y0 >= 1) && (y0 + 32 < H_);

    if (tid < 73) s_w[tid] = wf[tid];

    const unsigned short* gb = gated + (size_t)b * HW_ * 8;
    if (interior) {
        const unsigned short* gb0 = gb + ((size_t)(y0 - 1) * W_ + (x0 - 1)) * 8;
        for (int base = wv * 64; base < 1156; base += 256) {
            int px = base + lane;
            if (px < 1156) {
                int y = px / 34;
                async_cp16(&s_g[(size_t)base * 8],
                           &gb0[(size_t)(px + y * 266) * 8]);
            }
        }
    } else {
        for (int e = tid; e < 1156; e += 256) {
            int y = e / 34, x = e - y * 34;
            int gy = y0 + y - 1, gx = x0 + x - 1;
            u16x8 v = {0, 0, 0, 0, 0, 0, 0, 0};
            if (gy >= 0 && gy < H_ && gx >= 0 && gx < W_)
                v = *(const u16x8*)&gb[((size_t)gy * W_ + gx) * 8];
            *(u16x8*)&s_g[e * 8] = v;
        }
    }
    __syncthreads();

    int qx = (tid & 15) * 2, qy = (tid >> 4) * 2;
    float f[4];
    float gm = *gamma;
#pragma unroll
    for (int p = 0; p < 4; ++p) {
        int ly = qy + (p >> 1), lx = qx + (p & 1);
        float acc = s_w[72];
#pragma unroll
        for (int t = 0; t < 9; ++t) {
            u16x8 n = *(const u16x8*)&s_g[((ly + t / 3) * 34 + lx + t % 3) * 8];
#pragma unroll
            for (int ci = 0; ci < 8; ++ci) acc += b2f(n[ci]) * s_w[t * 8 + ci];
        }
        f[p] = (1.f - gm) + gm * sigm(acc);
    }

    int px = x0 + qx, py = y0 + qy;
    if (px < W_) {
#pragma unroll
        for (int ch = 0; ch < 3; ++ch) {
            const float* imb = im + ((size_t)b * 3 + ch) * HW_;
            float* ob = out + ((size_t)b * 3 + ch) * HW_;
#pragma unroll
            for (int pr = 0; pr < 2; ++pr) {
                if (py + pr < H_) {
                    float2 iv = *(const float2*)&imb[(size_t)(py + pr) * W_ + px];
                    float2 ov;
                    ov.x = iv.x * f[pr * 2 + 0];
                    ov.y = iv.y * f[pr * 2 + 1];
                    *(float2*)&ob[(size_t)(py + pr) * W_ + px] = ov;
                }
            }
        }
    }
}

// ---------------------------------------------------------------------------

extern "C" void kernel_launch(void* const* d_in, const int* in_sizes, int n_in,
                              void* d_out, int out_size, void* d_ws,
                              size_t ws_size, hipStream_t stream)
{
    (void)in_sizes; (void)n_in; (void)out_size;

    const float* im  = (const float*)d_in[0];
    const float* w1  = (const float*)d_in[1];
    const float* b1  = (const float*)d_in[2];
    const float* w2  = (const float*)d_in[3];
    const float* b2  = (const float*)d_in[4];
    const float* w3  = (const float*)d_in[5];
    const float* b3  = (const float*)d_in[6];
    const float* w4  = (const float*)d_in[7];
    const float* b4  = (const float*)d_in[8];
    const float* w5  = (const float*)d_in[9];
    const float* b5  = (const float*)d_in[10];
    const float* wc5 = (const float*)d_in[11];
    const float* bc5 = (const float*)d_in[12];
    const float* wc10= (const float*)d_in[13];
    const float* bc10= (const float*)d_in[14];
    const float* wc15= (const float*)d_in[15];
    const float* bc15= (const float*)d_in[16];
    const float* wg  = (const float*)d_in[17];
    const float* bg  = (const float*)d_in[18];
    const float* wm  = (const float*)d_in[19];
    const float* bm  = (const float*)d_in[20];
    const float* bnw = (const float*)d_in[21];
    const float* bnb = (const float*)d_in[22];
    const float* w11 = (const float*)d_in[23];
    const float* b11 = (const float*)d_in[24];
    const float* gam = (const float*)d_in[25];
    float* out = (float*)d_out;

    // ---- workspace plan (chunked batch; deterministic in ws_size) ----------
    const size_t GATED_B = 46080000;
    const size_t PER_IMG = 1440000 + 2880000 + 5760000 + 57600 + 14400 + 6656;
    const size_t MISC    = 1048576;
    int c = 32;
    while (c > 1 && GATED_B + MISC + (size_t)c * PER_IMG + 2048 > ws_size)
        c >>= 1;

    char* p = (char*)d_ws;
    auto take = [&](size_t bytes) {
        char* r = p;
        p += (bytes + 255) & ~(size_t)255;
        return r;
    };
    unsigned short* GATED = (unsigned short*)take(GATED_B);
    unsigned short* A   = (unsigned short*)take((size_t)c * 1440000);
    unsigned short* Bb  = (unsigned short*)take((size_t)c * 2880000);
    unsigned short* C   = (unsigned short*)take((size_t)c * 5760000);
    unsigned short* P5  = (unsigned short*)take((size_t)c * 57600);
    unsigned short* P10 = (unsigned short*)take((size_t)c * 14400);
    unsigned short* P15 = (unsigned short*)take((size_t)c * 6656);
    float2* parts  = (float2*)take((size_t)NPART * 8 * sizeof(float2));
    float2* parts2 = (float2*)take(64 * 8 * sizeof(float2));
    float*  wfold  = (float*)take(512);
    unsigned short* WP = (unsigned short*)take(65536);

    unsigned short* PK2 = WP;            // conv2: 3 steps
    unsigned short* PK3 = WP + 2048;     // conv3: 5x2
    unsigned short* PK4 = WP + 8192;     // conv4: 9
    unsigned short* PK5 = WP + 13312;    // conv5: 5
    unsigned short* PKc = WP + 16384;    // convc composite: 9x2
    unsigned short* PKg = WP + 25600;    // gated: 9
    unsigned short* PK1 = WP + 30720;    // conv1: 3

    dim3 blk(256);

    pack_all_k<<<dim3(7), blk, 0, stream>>>(w1, w2, w3, w4, w5, wc5, wc10, wc15,
                                            wg, wm, WP);

    for (int b0 = 0; b0 < NBATCH; b0 += c) {
        dim3 g32(10, 10, c);   // TH=32 kernels
        dim3 g16(10, 19, c);   // TH=16 kernels
        const float* imc = im + (size_t)b0 * 3 * HW_;

        fused12_k<<<g32, blk, 0, stream>>>(imc, PK1, b1, PK2, b2, Bb);

        mfconv_k<16, 16, 32, 2, 0, 32><<<g32, blk, 0, stream>>>(
            Bb, PK3, b3, nullptr, C, 32, 0, nullptr, 0);
        mfconv_k<32, 32, 16, 1, 0, 16><<<g16, blk, 0, stream>>>(
            C, PK4, b4, nullptr, Bb, 16, 0, nullptr, 0);
        mfconv_k<16, 16, 8, 1, 0, 32><<<g32, blk, 0, stream>>>(
            Bb, PK5, b5, nullptr, A, 8, 0, nullptr, 0);

        int n5 = c * 3600, n10 = c * 900, n15 = c * 400;
        pool5_k<<<dim3((n5 + 255) / 256), blk, 0, stream>>>(A, P5, n5);
        poolrs_k<<<dim3((n10 + n15 + 255) / 256), blk, 0, stream>>>(P5, P10, P15,
                                                                    n10, n15);

        convc3_k<<<g16, blk, 0, stream>>>(A, P5, P10, P15, PKc, bc5, bc10, bc15, C);

        mfconv_k<24, 32, 16, 1, 2, 16><<<g16, blk, 0, stream>>>(
            C, PKg, bg, bm, GATED + (size_t)b0 * HW_ * 8, 8, 0, parts, b0);
    }

    reduce_parts_k<<<dim3(64), blk, 0, stream>>>(parts, parts2);
    stats_fold_k<<<dim3(1), blk, 0, stream>>>(parts2, bnw, bnb, w11, b11, wfold);
    final_k<<<dim3(10, 10, NBATCH), blk, 0, stream>>>(GATED, wfold, im, gam,
                                                      out);
}

// Round 14
// 404.390 us; speedup vs baseline: 1.1095x; 1.0215x over previous
//
#include <hip/hip_runtime.h>
#include <hip/hip_bf16.h>
#include <math.h>

typedef __hip_bfloat16 bf16;
typedef __attribute__((ext_vector_type(8))) __bf16 bf16x8;
typedef __attribute__((ext_vector_type(8))) unsigned short u16x8;
typedef __attribute__((ext_vector_type(4))) float f32x4;

#define H_ 300
#define W_ 300
#define HW_ 90000
#define NBATCH 32
#define NPART (NBATCH * 190)   // gated BN partials: one per gated (image,tile)
#define NPB 95                 // partial rows per reduce_parts block (6080/64)

__device__ __forceinline__ float b2f(unsigned short u) {
    return __uint_as_float((unsigned int)u << 16);
}
__device__ __forceinline__ unsigned short f2u(float v) {
    bf16 b = __float2bfloat16(v);
    return *reinterpret_cast<unsigned short*>(&b);
}
__device__ __forceinline__ float sigm(float x) { return 1.f / (1.f + __expf(-x)); }
// HW packed fp32->bf16 pair (RNE), 1 instr vs ~10 for the manual sequence.
__device__ __forceinline__ unsigned int packbf(float a, float b) {
    unsigned int r;
    asm("v_cvt_pk_bf16_f32 %0, %1, %2" : "=v"(r) : "v"(a), "v"(b));
    return r;
}
// Async global->LDS DMA, 16B per lane. LDS dest = wave-uniform base + lane*16;
// global src is per-lane. vmcnt drained by the compiler before s_barrier.
__device__ __forceinline__ void async_cp16(void* lds_base, const void* g) {
    __builtin_amdgcn_global_load_lds(
        (const __attribute__((address_space(1))) unsigned int*)g,
        (__attribute__((address_space(3))) unsigned int*)lds_base, 16, 0, 0);
}

// ---------------------------------------------------------------------------
// All weight prepacks in ONE launch (7 blocks). Fragment order: A operand,
// row = lane&15 = co, k = (lane>>4)*8+j; pack[step][g][lane][j] bf16.
// Block 4 is the convc composite (see convc3_k).
// ---------------------------------------------------------------------------
__global__ void pack_all_k(
    const float* __restrict__ w1, const float* __restrict__ w2,
    const float* __restrict__ w3, const float* __restrict__ w4,
    const float* __restrict__ w5, const float* __restrict__ wc5,
    const float* __restrict__ wc10, const float* __restrict__ wc15,
    const float* __restrict__ wg, const float* __restrict__ wm,
    unsigned short* __restrict__ WP)
{
    const float *a = nullptr, *bsec = nullptr;
    int cs = 999, CO = 0, CI = 0, CP = 8, NS = 3, NG = 1, off = 0, special = 0;
    switch (blockIdx.x) {
        case 0: a = w2;  CO = 16; CI = 8;  CP = 8;  NS = 3; off = 0;     break;
        case 1: a = w3;  CO = 32; CI = 16; CP = 16; NS = 5; NG = 2; off = 2048;  break;
        case 2: a = w4;  CO = 16; CI = 32; CP = 32; NS = 9; off = 8192;  break;
        case 3: a = w5;  CO = 8;  CI = 16; CP = 16; NS = 5; off = 13312; break;
        case 4: special = 1; CO = 32; CI = 32; CP = 32; NS = 9; NG = 2;
                off = 16384; break;
        case 5: a = wg; bsec = wm; cs = 8; CO = 16; CI = 24; CP = 32; NS = 9;
                off = 25600; break;
        case 6: a = w1;  CO = 8;  CI = 3;  CP = 8;  NS = 3; off = 30720; break;
    }
    unsigned short* outp = WP + off;
    int TPK = 32 / CP;
    int total = NS * NG * 512;
    for (int idx = threadIdx.x; idx < total; idx += 256) {
        int j = idx & 7;
        int lane = (idx >> 3) & 63;
        int g = (idx >> 9) % NG;
        int s = idx / (512 * NG);
        int col = lane & 15, kg = lane >> 4;
        int kk = kg * 8 + j;
        int tt = kk / CP, ci = kk % CP;
        int tap = s * TPK + tt;
        float v = 0.f;
        if (special) {
            int o = ci >> 3, c8 = ci & 7;
            int convid = (g == 0) ? (col < 8 ? 0 : 1) : (col < 8 ? 2 : -1);
            if (tap < 9 && convid >= 0) {
                const float* wc = (convid == 0) ? wc5 : (convid == 1) ? wc10 : wc15;
                int colc = col & 7;
                if (o == 0) v = wc[(colc * 16 + c8) * 9 + tap];
                else if (o == convid + 1) v = wc[(colc * 16 + 8 + c8) * 9 + tap];
            }
        } else {
            int co = g * 16 + col;
            if (tap < 9 && ci < CI && co < CO)
                v = (co >= cs) ? bsec[((co - cs) * CI + ci) * 9 + tap]
                               : a[(co * CI + ci) * 9 + tap];
        }
        outp[idx] = f2u(v);
    }
}

// ---------------------------------------------------------------------------
// Fused conv1+conv2: one 32x32 output tile of x2 (see round-13 notes).
// ---------------------------------------------------------------------------
__global__ __launch_bounds__(256) void fused12_k(
    const float* __restrict__ im, const unsigned short* __restrict__ wp1,
    const float* __restrict__ b1, const unsigned short* __restrict__ wp2,
    const float* __restrict__ b2, unsigned short* __restrict__ out)
{
    __shared__ __align__(16) unsigned short s_im[1296 * 8];   // 36x36
    __shared__ __align__(16) unsigned short s_x1[1156 * 8];   // 34x34

    int b = blockIdx.z;
    int x0 = blockIdx.x * 32, y0 = blockIdx.y * 32;
    int tid = threadIdx.x;
    int lane = tid & 63, wv = tid >> 6;
    int col = lane & 15, kg = lane >> 4;

    const float* sf = im + (size_t)b * 3 * HW_;
    bool interior = (x0 >= 2) && (x0 + 34 < W_) && (y0 >= 2) && (y0 + 34 < H_);
    if (interior) {
        const float* sf0 = sf + (size_t)(y0 - 2) * W_ + (x0 - 2);
        for (int e = tid; e < 1296; e += 256) {
            int y = e / 36;
            size_t o = (size_t)e + (size_t)y * 264;
            u16x8 v = {0, 0, 0, 0, 0, 0, 0, 0};
            v[0] = f2u(sf0[o]);
            v[1] = f2u(sf0[HW_ + o]);
            v[2] = f2u(sf0[2 * HW_ + o]);
            *(u16x8*)&s_im[e * 8] = v;
        }
    } else {
        for (int e = tid; e < 1296; e += 256) {
            int y = e / 36, x = e - y * 36;
            int gy = y0 + y - 2, gx = x0 + x - 2;
            u16x8 v = {0, 0, 0, 0, 0, 0, 0, 0};
            if (gy >= 0 && gy < H_ && gx >= 0 && gx < W_) {
                size_t o = (size_t)gy * W_ + gx;
                v[0] = f2u(sf[o]);
                v[1] = f2u(sf[HW_ + o]);
                v[2] = f2u(sf[2 * HW_ + o]);
            }
            *(u16x8*)&s_im[e * 8] = v;
        }
    }

    bf16x8 bw1[3], bw2[3];
#pragma unroll
    for (int s = 0; s < 3; ++s) {
        bw1[s] = *(const bf16x8*)&wp1[(s * 64 + lane) * 8];
        bw2[s] = *(const bf16x8*)&wp2[(s * 64 + lane) * 8];
    }

    int offs1[3], offs2[3];
#pragma unroll
    for (int s = 0; s < 3; ++s) {
        int t = s * 4 + kg;
        if (t > 8) t = 8;
        offs1[s] = ((t / 3) * 36 + (t % 3)) * 8;
        offs2[s] = ((t / 3) * 34 + (t % 3)) * 8;
    }

    float b1r[4], b2r[4];
#pragma unroll
    for (int r = 0; r < 4; ++r) {
        int co1 = kg * 4 + r;
        b1r[r] = (co1 < 8) ? b1[co1] : 0.f;
        b2r[r] = b2[kg * 4 + r];
    }

    __syncthreads();

    for (int r = wv; r < 34; r += 4) {
#pragma unroll
        for (int cg = 0; cg < 3; ++cg) {
            int base = (r * 36 + cg * 16 + col) * 8;
            f32x4 acc = {0.f, 0.f, 0.f, 0.f};
#pragma unroll
            for (int s = 0; s < 3; ++s) {
                bf16x8 a = *(const bf16x8*)&s_im[base + offs1[s]];
                acc = __builtin_amdgcn_mfma_f32_16x16x32_bf16(bw1[s], a, acc, 0, 0, 0);
            }
            int c = cg * 16 + col;
            if (kg < 2 && c < 34) {
                int gy = y0 - 1 + r, gx = x0 - 1 + c;
                bool ok = (gy >= 0) && (gy < H_) && (gx >= 0) && (gx < W_);
                float o0 = ok ? acc.x + b1r[0] : 0.f;
                float o1 = ok ? acc.y + b1r[1] : 0.f;
                float o2 = ok ? acc.z + b1r[2] : 0.f;
                float o3 = ok ? acc.w + b1r[3] : 0.f;
                uint2 st;
                st.x = packbf(o0, o1);
                st.y = packbf(o2, o3);
                *(uint2*)&s_x1[(r * 34 + c) * 8 + kg * 4] = st;
            }
        }
    }
    __syncthreads();

#pragma unroll
    for (int i = 0; i < 16; ++i) {
        int m = wv * 16 + i;
        int my = m >> 1, tx = m & 1;
        int gy = y0 + my;
        if (gy >= H_) continue;
        int base = (my * 34 + tx * 16 + col) * 8;

        f32x4 acc = {0.f, 0.f, 0.f, 0.f};
#pragma unroll
        for (int s = 0; s < 3; ++s) {
            bf16x8 a = *(const bf16x8*)&s_x1[base + offs2[s]];
            acc = __builtin_amdgcn_mfma_f32_16x16x32_bf16(bw2[s], a, acc, 0, 0, 0);
        }

        int gxx = x0 + tx * 16 + col;
        if (gxx < W_) {
            uint2 st;
            st.x = packbf(acc.x + b2r[0], acc.y + b2r[1]);
            st.y = packbf(acc.z + b2r[2], acc.w + b2r[3]);
            *(uint2*)&out[((size_t)b * HW_ + (size_t)gy * W_ + gxx) * 16 +
                          kg * 4] = st;
        }
    }
}

// ---------------------------------------------------------------------------
// MFMA implicit-GEMM 3x3 conv (unchanged from round 13).
// ---------------------------------------------------------------------------
template <int CIN, int CINP, int COUT, int NGI, int MODE, int TH>
__global__ __launch_bounds__(256) void mfconv_k(
    const unsigned short* __restrict__ src,
    const unsigned short* __restrict__ wpack,
    const float* __restrict__ bias0, const float* __restrict__ bias1,
    unsigned short* __restrict__ out, int co_total, int co_off,
    float2* __restrict__ bnp, int img_base)
{
    constexpr int TPK = 32 / CINP;
    constexpr int NSTEP = (9 + TPK - 1) / TPK;
    constexpr int OCT = CINP / 8;
    constexpr int NPX = (TH + 2) * 34;
    constexpr int STRIDE = 256 / OCT;

    __shared__ __align__(16) unsigned short s_in[OCT * NPX * 8];

    int b = blockIdx.z;
    int x0 = blockIdx.x * 32, y0 = blockIdx.y * TH;
    int tid = threadIdx.x;
    int lane = tid & 63, wv = tid >> 6;
    bool interior = (x0 >= 1) && (x0 + 32 < W_) && (y0 >= 1) && (y0 + TH < H_);

    int oct = (OCT == 1) ? 0 : (wv % OCT);
    int phase = (OCT == 4) ? 0 : (wv / OCT);
    bool voct = (CIN == CINP) || (oct * 8 < CIN);

    {
        const unsigned short* sb = src + (size_t)b * CIN * HW_;
        if (interior) {
            if (voct) {
                const unsigned short* sb0 =
                    sb + ((size_t)(y0 - 1) * W_ + (x0 - 1)) * CIN + oct * 8;
#pragma unroll
                for (int pxb = 0; pxb < NPX; pxb += STRIDE) {
                    int base = phase * 64 + pxb;
                    if (base >= NPX) break;
                    int px = base + lane;
                    if (px < NPX) {
                        int y = px / 34;
                        async_cp16(&s_in[(oct * NPX + base) * 8],
                                   &sb0[(size_t)(px + y * 266) * CIN]);
                    }
                }
            } else {
                u16x8 z8 = {0, 0, 0, 0, 0, 0, 0, 0};
                for (int px = lane + phase * 64; px < NPX; px += STRIDE)
                    *(u16x8*)&s_in[(oct * NPX + px) * 8] = z8;
            }
        } else {
            for (int px = lane + phase * 64; px < NPX; px += STRIDE) {
                int y = px / 34, x = px - y * 34;
                int gy = y0 + y - 1, gx = x0 + x - 1;
                u16x8 v = {0, 0, 0, 0, 0, 0, 0, 0};
                if (gy >= 0 && gy < H_ && gx >= 0 && gx < W_ && voct)
                    v = *(const u16x8*)&sb[((size_t)gy * W_ + gx) * CIN + oct * 8];
                *(u16x8*)&s_in[(oct * NPX + px) * 8] = v;
            }
        }
    }

    bf16x8 bw[NGI][NSTEP];
#pragma unroll
    for (int gi = 0; gi < NGI; ++gi)
#pragma unroll
        for (int s = 0; s < NSTEP; ++s)
            bw[gi][s] = *(const bf16x8*)&wpack[((s * NGI + gi) * 64 + lane) * 8];

    int col = lane & 15, kg = lane >> 4;

    float bias_r[NGI][4];
#pragma unroll
    for (int gi = 0; gi < NGI; ++gi)
#pragma unroll
        for (int r = 0; r < 4; ++r) {
            if (MODE == 2)
                bias_r[0][r] = (kg < 2) ? bias0[kg * 4 + r] : bias1[(kg - 2) * 4 + r];
            else {
                int co_l = gi * 16 + kg * 4 + r;
                bias_r[gi][r] = (co_l < COUT) ? bias0[co_l] : 0.f;
            }
        }

    float bs[4] = {0.f, 0.f, 0.f, 0.f}, bs2[4] = {0.f, 0.f, 0.f, 0.f};

    __syncthreads();

    if constexpr (OCT == 4) {
        int myb = wv * (TH / 4);
#pragma unroll
        for (int tx = 0; tx < 2; ++tx) {
            int pbase = kg * NPX + tx * 16 + col;
            bf16x8 fr[3][3];
#pragma unroll
            for (int r = 0; r < 2; ++r)
#pragma unroll
                for (int dx = 0; dx < 3; ++dx)
                    fr[r][dx] =
                        *(const bf16x8*)&s_in[(pbase + (myb + r) * 34 + dx) * 8];
#pragma unroll
            for (int ii = 0; ii < TH / 4; ++ii) {
#pragma unroll
                for (int dx = 0; dx < 3; ++dx)
                    fr[(ii + 2) % 3][dx] =
                        *(const bf16x8*)&s_in[(pbase + (myb + ii + 2) * 34 + dx) * 8];

                f32x4 acc[NGI];
#pragma unroll
                for (int gi = 0; gi < NGI; ++gi) acc[gi] = {0.f, 0.f, 0.f, 0.f};
#pragma unroll
                for (int dy = 0; dy < 3; ++dy)
#pragma unroll
                    for (int dx = 0; dx < 3; ++dx) {
                        bf16x8 a = fr[(ii + dy) % 3][dx];
#pragma unroll
                        for (int gi = 0; gi < NGI; ++gi)
                            acc[gi] = __builtin_amdgcn_mfma_f32_16x16x32_bf16(
                                bw[gi][dy * 3 + dx], a, acc[gi], 0, 0, 0);
                    }

                int gy = y0 + myb + ii;
                int gxx = x0 + tx * 16 + col;
                if (gy < H_) {
                    if (MODE == 2) {
                        float v0 = acc[0].x + bias_r[0][0];
                        float v1 = acc[0].y + bias_r[0][1];
                        float v2 = acc[0].z + bias_r[0][2];
                        float v3 = acc[0].w + bias_r[0][3];
                        float m0 = __shfl_xor(v0, 32), m1 = __shfl_xor(v1, 32);
                        float m2 = __shfl_xor(v2, 32), m3 = __shfl_xor(v3, 32);
                        if (kg < 2 && gxx < W_) {
                            float o0 = v0 * sigm(m0), o1 = v1 * sigm(m1);
                            float o2 = v2 * sigm(m2), o3 = v3 * sigm(m3);
                            uint2 st;
                            st.x = packbf(o0, o1);
                            st.y = packbf(o2, o3);
                            *(uint2*)&out[(((size_t)b * HW_ + (size_t)gy * W_ +
                                            gxx) * 8) + kg * 4] = st;
                            bs[0] += o0; bs2[0] += o0 * o0;
                            bs[1] += o1; bs2[1] += o1 * o1;
                            bs[2] += o2; bs2[2] += o2 * o2;
                            bs[3] += o3; bs2[3] += o3 * o3;
                        }
                    } else {
#pragma unroll
                        for (int gi = 0; gi < NGI; ++gi) {
                            int co_g = gi * 16 + kg * 4;
                            if (co_g < COUT && gxx < W_) {
                                uint2 st;
                                st.x = packbf(acc[gi].x + bias_r[gi][0],
                                              acc[gi].y + bias_r[gi][1]);
                                st.y = packbf(acc[gi].z + bias_r[gi][2],
                                              acc[gi].w + bias_r[gi][3]);
                                *(uint2*)&out[((size_t)b * HW_ +
                                               (size_t)gy * W_ + gxx) *
                                                  co_total + co_off + co_g] = st;
                            }
                        }
                    }
                }
            }
        }
    } else {
        int offs[NSTEP];
#pragma unroll
        for (int s = 0; s < NSTEP; ++s) {
            int t = s * TPK + kg / OCT;
            if (t > 8) t = 8;
            offs[s] = ((t / 3) * 34 + (t % 3)) * 8 + (kg % OCT) * (NPX * 8);
        }

#pragma unroll
        for (int i = 0; i < TH / 2; ++i) {
            int m = wv * (TH / 2) + i;
            int my = m >> 1, tx = m & 1;
            int gy = y0 + my;
            if (gy >= H_) continue;
            int base = (my * 34 + tx * 16 + col) * 8;

            f32x4 acc[NGI];
#pragma unroll
            for (int gi = 0; gi < NGI; ++gi) acc[gi] = {0.f, 0.f, 0.f, 0.f};
#pragma unroll
            for (int s = 0; s < NSTEP; ++s) {
                bf16x8 a = *(const bf16x8*)&s_in[base + offs[s]];
#pragma unroll
                for (int gi = 0; gi < NGI; ++gi)
                    acc[gi] = __builtin_amdgcn_mfma_f32_16x16x32_bf16(
                        bw[gi][s], a, acc[gi], 0, 0, 0);
            }

            int gxx = x0 + tx * 16 + col;
#pragma unroll
            for (int gi = 0; gi < NGI; ++gi) {
                int co_g = gi * 16 + kg * 4;
                if (co_g < COUT && gxx < W_) {
                    uint2 st;
                    st.x = packbf(acc[gi].x + bias_r[gi][0],
                                  acc[gi].y + bias_r[gi][1]);
                    st.y = packbf(acc[gi].z + bias_r[gi][2],
                                  acc[gi].w + bias_r[gi][3]);
                    *(uint2*)&out[((size_t)b * HW_ + (size_t)gy * W_ + gxx) *
                                      co_total + co_off + co_g] = st;
                }
            }
        }
    }

    if constexpr (MODE == 2) {
#pragma unroll
        for (int off = 1; off < 16; off <<= 1) {
#pragma unroll
            for (int r = 0; r < 4; ++r) {
                bs[r] += __shfl_xor(bs[r], off);
                bs2[r] += __shfl_xor(bs2[r], off);
            }
        }
        __shared__ float bsum[4][8], bsq[4][8];
        if (lane == 0) {
#pragma unroll
            for (int r = 0; r < 4; ++r) { bsum[wv][r] = bs[r]; bsq[wv][r] = bs2[r]; }
        }
        if (lane == 16) {
#pragma unroll
            for (int r = 0; r < 4; ++r) {
                bsum[wv][4 + r] = bs[r];
                bsq[wv][4 + r] = bs2[r];
            }
        }
        __syncthreads();
        if (tid < 8) {
            float s = 0.f, s2 = 0.f;
#pragma unroll
            for (int w = 0; w < 4; ++w) { s += bsum[w][tid]; s2 += bsq[w][tid]; }
            int bIdx = (img_base + b) * 190 + blockIdx.y * 10 + blockIdx.x;
            bnp[(size_t)bIdx * 8 + tid] = make_float2(s, s2);
        }
    }
}

// ---------------------------------------------------------------------------
// Fused cK trio, v2: TH=32, tiny pool TABLES in LDS instead of expanded
// planes. Lane's A-fragment for pool plane k is pK[gy/K][gx/K] (16B octet),
// read directly from the table via magic-div addressing; OOB -> zero
// sentinel (exact zero-pad semantics). LDS 39.4KB -> 20.4KB => occupancy up.
// Table spans (TH=32 tile + halo): p5 8x9, p10 5x5, p15 4x4.
// ---------------------------------------------------------------------------
#define C3_NPX 1156            // 34x34 x-plane pixels
#define C3_T5  0               // p5 table base (octets), 72
#define C3_T10 72              // p10 base, 25
#define C3_T15 97              // p15 base, 16
#define C3_SENT 113            // zero sentinel octet
#define C3_TBL 120             // table octet count (padded)

__global__ __launch_bounds__(256) void convc3_k(
    const unsigned short* __restrict__ src,
    const unsigned short* __restrict__ p5, const unsigned short* __restrict__ p10,
    const unsigned short* __restrict__ p15,
    const unsigned short* __restrict__ wpack,
    const float* __restrict__ bc5, const float* __restrict__ bc10,
    const float* __restrict__ bc15, unsigned short* __restrict__ out)
{
    constexpr int TH = 32;
    __shared__ __align__(16) unsigned short s_all[(C3_NPX + C3_TBL) * 8];

    int b = blockIdx.z;
    int x0 = blockIdx.x * 32, y0 = blockIdx.y * TH;
    int tid = threadIdx.x;
    int lane = tid & 63, wv = tid >> 6;
    bool interior = (x0 >= 1) && (x0 + 32 < W_) && (y0 >= 1) && (y0 + TH < H_);

    const unsigned short* sb = src + (size_t)b * 8 * HW_;
    const unsigned short* pb5 = p5 + (size_t)b * 8 * 3600;
    const unsigned short* pb10 = p10 + (size_t)b * 8 * 900;
    const unsigned short* pb15 = p15 + (size_t)b * 8 * 400;

    // block-uniform table origins
    int ylo = (y0 - 1 < 0) ? 0 : y0 - 1;
    int xlo = (x0 - 1 < 0) ? 0 : x0 - 1;
    int yb5 = ylo / 5, xb5 = xlo / 5;
    int yb10 = ylo / 10, xb10 = xlo / 10;
    int yb15 = ylo / 15, xb15 = xlo / 15;

    // ---- stage x plane (DMA when interior) ----
    if (interior) {
        const unsigned short* sb0 = sb + ((size_t)(y0 - 1) * W_ + (x0 - 1)) * 8;
        for (int base = wv * 64; base < C3_NPX; base += 256) {
            int px = base + lane;
            if (px < C3_NPX) {
                int y = px / 34;
                async_cp16(&s_all[(size_t)base * 8],
                           &sb0[(size_t)(px + y * 266) * 8]);
            }
        }
    } else {
        for (int px = tid; px < C3_NPX; px += 256) {
            int y = px / 34, x = px - y * 34;
            int gy = y0 + y - 1, gx = x0 + x - 1;
            u16x8 v = {0, 0, 0, 0, 0, 0, 0, 0};
            if (gy >= 0 && gy < H_ && gx >= 0 && gx < W_)
                v = *(const u16x8*)&sb[((size_t)gy * W_ + gx) * 8];
            *(u16x8*)&s_all[px * 8] = v;
        }
    }

    // ---- stage pool tables (clamped; OOB lanes use sentinel at read) ----
    if (tid < 72) {
        int r = tid / 9, cc = tid - r * 9;
        int yi = yb5 + r; if (yi > 59) yi = 59;
        int xi = xb5 + cc; if (xi > 59) xi = 59;
        *(u16x8*)&s_all[(C3_NPX + C3_T5 + tid) * 8] =
            *(const u16x8*)&pb5[((size_t)yi * 60 + xi) * 8];
    } else if (tid < 97) {
        int t = tid - 72;
        int r = t / 5, cc = t - r * 5;
        int yi = yb10 + r; if (yi > 29) yi = 29;
        int xi = xb10 + cc; if (xi > 29) xi = 29;
        *(u16x8*)&s_all[(C3_NPX + C3_T10 + t) * 8] =
            *(const u16x8*)&pb10[((size_t)yi * 30 + xi) * 8];
    } else if (tid < 113) {
        int t = tid - 97;
        int r = t / 4, cc = t - r * 4;
        int yi = yb15 + r; if (yi > 19) yi = 19;
        int xi = xb15 + cc; if (xi > 19) xi = 19;
        *(u16x8*)&s_all[(C3_NPX + C3_T15 + t) * 8] =
            *(const u16x8*)&pb15[((size_t)yi * 20 + xi) * 8];
    } else if (tid == 113) {
        u16x8 z = {0, 0, 0, 0, 0, 0, 0, 0};
        *(u16x8*)&s_all[(C3_NPX + C3_SENT) * 8] = z;
    }

    bf16x8 bw[2][9];
#pragma unroll
    for (int g = 0; g < 2; ++g)
#pragma unroll
        for (int s = 0; s < 9; ++s)
            bw[g][s] = *(const bf16x8*)&wpack[((s * 2 + g) * 64 + lane) * 8];

    int col = lane & 15, kg = lane >> 4;
    float bias_r[2][4];
#pragma unroll
    for (int r = 0; r < 4; ++r) {
        bias_r[0][r] = (kg < 2) ? bc5[kg * 4 + r] : bc10[(kg - 2) * 4 + r];
        bias_r[1][r] = (kg < 2) ? bc15[kg * 4 + r] : 0.f;
    }

    // per-lane pool addressing constants (kg>=1; kg==0 unused)
    unsigned int M = (kg == 1) ? 13108u : (kg == 2) ? 6554u : 4370u;
    int ybk = (kg == 1) ? yb5 : (kg == 2) ? yb10 : yb15;
    int xbk = (kg == 1) ? xb5 : (kg == 2) ? xb10 : xb15;
    int TWk = (kg == 1) ? 9 : (kg == 2) ? 5 : 4;
    int tbk = C3_NPX + ((kg == 1) ? C3_T5 : (kg == 2) ? C3_T10 : C3_T15);

    __syncthreads();

    int myb = wv * (TH / 4);
#pragma unroll
    for (int tx = 0; tx < 2; ++tx) {
        int pbx = tx * 16 + col;
        int gx0 = x0 - 1 + pbx;
        // per-dx x table index + validity (lane-constant across rows)
        int xrel[3];
        bool xok[3];
#pragma unroll
        for (int dx = 0; dx < 3; ++dx) {
            int gx = gx0 + dx;
            xok[dx] = ((unsigned)gx < (unsigned)W_);
            int gxc = gx < 0 ? 0 : gx;
            xrel[dx] = (int)(((unsigned)gxc * M) >> 16) - xbk;
        }

        auto frag_off = [&](int r, int dx, int prow, bool yok) -> int {
            if (kg == 0) return (r * 34 + pbx + dx) * 8;
            bool ok = yok && xok[dx];
            return ok ? (prow + xrel[dx]) * 8 : (C3_NPX + C3_SENT) * 8;
        };
        auto row_prow = [&](int r, bool& yok) -> int {
            int gy = y0 - 1 + r;
            yok = ((unsigned)gy < (unsigned)H_);
            int gyc = gy < 0 ? 0 : gy;
            int yidx = (int)(((unsigned)gyc * M) >> 16);
            return tbk + (yidx - ybk) * TWk;
        };

        bf16x8 fr[3][3];
#pragma unroll
        for (int r = 0; r < 2; ++r) {
            bool yok;
            int prow = row_prow(myb + r, yok);
#pragma unroll
            for (int dx = 0; dx < 3; ++dx)
                fr[r][dx] = *(const bf16x8*)&s_all[frag_off(myb + r, dx, prow, yok)];
        }
#pragma unroll
        for (int ii = 0; ii < TH / 4; ++ii) {
            {
                bool yok;
                int prow = row_prow(myb + ii + 2, yok);
#pragma unroll
                for (int dx = 0; dx < 3; ++dx)
                    fr[(ii + 2) % 3][dx] =
                        *(const bf16x8*)&s_all[frag_off(myb + ii + 2, dx, prow, yok)];
            }

            f32x4 acc[2];
            acc[0] = {0.f, 0.f, 0.f, 0.f};
            acc[1] = {0.f, 0.f, 0.f, 0.f};
#pragma unroll
            for (int dy = 0; dy < 3; ++dy)
#pragma unroll
                for (int dx = 0; dx < 3; ++dx) {
                    bf16x8 a = fr[(ii + dy) % 3][dx];
                    acc[0] = __builtin_amdgcn_mfma_f32_16x16x32_bf16(
                        bw[0][dy * 3 + dx], a, acc[0], 0, 0, 0);
                    acc[1] = __builtin_amdgcn_mfma_f32_16x16x32_bf16(
                        bw[1][dy * 3 + dx], a, acc[1], 0, 0, 0);
                }

            int gy = y0 + myb + ii;
            int gxx = x0 + tx * 16 + col;
            if (gy < H_ && gxx < W_) {
                size_t pxo = ((size_t)b * HW_ + (size_t)gy * W_ + gxx) * 24;
                uint2 st0;
                st0.x = packbf(acc[0].x + bias_r[0][0], acc[0].y + bias_r[0][1]);
                st0.y = packbf(acc[0].z + bias_r[0][2], acc[0].w + bias_r[0][3]);
                *(uint2*)&out[pxo + kg * 4] = st0;  // ch 0-15: c5|c10
                if (kg < 2) {
                    uint2 st1;
                    st1.x = packbf(acc[1].x + bias_r[1][0], acc[1].y + bias_r[1][1]);
                    st1.y = packbf(acc[1].z + bias_r[1][2], acc[1].w + bias_r[1][3]);
                    *(uint2*)&out[pxo + 16 + kg * 4] = st1;  // ch 16-23: c15
                }
            }
        }
    }
}

// ---------------------------------------------------------------------------
// Pools, NHWC. p5 from x; p10/p15 from p5 (hierarchical).
// ---------------------------------------------------------------------------
__global__ __launch_bounds__(256) void pool5_k(const unsigned short* __restrict__ x,
                                               unsigned short* __restrict__ p5,
                                               int n)
{
    int idx = blockIdx.x * 256 + threadIdx.x;
    if (idx >= n) return;
    int b = idx / 3600;
    int rem = idx - b * 3600;
    int i = rem / 60, j = rem - i * 60;
    const unsigned short* src =
        x + ((size_t)b * HW_ + (size_t)(i * 5) * W_ + j * 5) * 8;
    float ss[8] = {0, 0, 0, 0, 0, 0, 0, 0};
#pragma unroll
    for (int r = 0; r < 5; ++r)
#pragma unroll
        for (int c = 0; c < 5; ++c) {
            u16x8 v = *(const u16x8*)&src[((size_t)r * W_ + c) * 8];
#pragma unroll
            for (int k = 0; k < 8; ++k) ss[k] += b2f(v[k]);
        }
    uint4 st;
    st.x = packbf(ss[0] * 0.04f, ss[1] * 0.04f);
    st.y = packbf(ss[2] * 0.04f, ss[3] * 0.04f);
    st.z = packbf(ss[4] * 0.04f, ss[5] * 0.04f);
    st.w = packbf(ss[6] * 0.04f, ss[7] * 0.04f);
    *(uint4*)&p5[(size_t)idx * 8] = st;
}

template <int R, int OD>
__device__ __forceinline__ void poolr_body(const unsigned short* __restrict__ p5,
                                           unsigned short* __restrict__ po, int idx)
{
    int b = idx / (OD * OD);
    int rem = idx - b * OD * OD;
    int i = rem / OD, j = rem - i * OD;
    const unsigned short* src =
        p5 + ((size_t)b * 3600 + (size_t)(i * R) * 60 + j * R) * 8;
    float ss[8] = {0, 0, 0, 0, 0, 0, 0, 0};
    const float inv = 1.f / (R * R);
#pragma unroll
    for (int r = 0; r < R; ++r)
#pragma unroll
        for (int c = 0; c < R; ++c) {
            u16x8 v = *(const u16x8*)&src[((size_t)r * 60 + c) * 8];
#pragma unroll
            for (int k = 0; k < 8; ++k) ss[k] += b2f(v[k]);
        }
    uint4 st;
    st.x = packbf(ss[0] * inv, ss[1] * inv);
    st.y = packbf(ss[2] * inv, ss[3] * inv);
    st.z = packbf(ss[4] * inv, ss[5] * inv);
    st.w = packbf(ss[6] * inv, ss[7] * inv);
    *(uint4*)&po[(size_t)idx * 8] = st;
}

__global__ __launch_bounds__(256) void poolrs_k(const unsigned short* __restrict__ p5,
                                                unsigned short* __restrict__ p10,
                                                unsigned short* __restrict__ p15,
                                                int n10, int n15)
{
    int idx = blockIdx.x * 256 + threadIdx.x;
    if (idx < n10) {
        poolr_body<2, 30>(p5, p10, idx);
    } else {
        idx -= n10;
        if (idx < n15) poolr_body<3, 20>(p5, p15, idx);
    }
}

// ---------------------------------------------------------------------------
// Stage A: collapse NPART block-partials to 64 rows (parallel, coalesced).
// ---------------------------------------------------------------------------
__global__ __launch_bounds__(256) void reduce_parts_k(
    const float2* __restrict__ parts, float2* __restrict__ parts2)
{
    int k = blockIdx.x;
    int tid = threadIdx.x;
    int c = tid & 7, j = tid >> 3;
    float s = 0.f, s2 = 0.f;
    for (int r = j; r < NPB; r += 32) {
        float2 p = parts[((size_t)k * NPB + r) * 8 + c];
        s += p.x;
        s2 += p.y;
    }
    __shared__ float2 red[256];
    red[tid] = make_float2(s, s2);
    __syncthreads();
    if (tid < 8) {
        float a = 0.f, b = 0.f;
        for (int q = 0; q < 32; ++q) {
            float2 p = red[q * 8 + tid];
            a += p.x;
            b += p.y;
        }
        parts2[(size_t)k * 8 + tid] = make_float2(a, b);
    }
}

// Stage B: reduce 64 rows, fold BN into conv11 weights; wfold[t*8+ci], [72]=bias.
__global__ __launch_bounds__(256) void stats_fold_k(
    const float2* __restrict__ parts2, const float* __restrict__ bn_w,
    const float* __restrict__ bn_b, const float* __restrict__ w11,
    const float* __restrict__ b11, float* __restrict__ wfold)
{
    __shared__ float sc[8], tc[8];
    __shared__ float2 acc8[8];
    int tid = threadIdx.x;
    int c = tid >> 5, sl = tid & 31;
    float s = 0.f, s2 = 0.f;
    for (int i = sl; i < 64; i += 32) {
        float2 p = parts2[(size_t)i * 8 + c];
        s += p.x;
        s2 += p.y;
    }
#pragma unroll
    for (int off = 16; off > 0; off >>= 1) {
        s += __shfl_down(s, off, 32);
        s2 += __shfl_down(s2, off, 32);
    }
    if (sl == 0) acc8[c] = make_float2(s, s2);
    __syncthreads();
    if (tid < 8) {
        double ds = acc8[tid].x, ds2 = acc8[tid].y;
        double N = (double)NBATCH * HW_;
        double mean = ds / N;
        double var = ds2 / N - mean * mean;
        float rstd = (float)(1.0 / sqrt(var + 1e-5));
        float scv = bn_w[tid] * rstd;
        sc[tid] = scv;
        tc[tid] = bn_b[tid] - (float)mean * scv;
    }
    __syncthreads();
    if (tid < 72) {
        int t = tid >> 3, ci = tid & 7;
        wfold[tid] = w11[ci * 9 + t] * sc[ci];
    }
    if (tid == 72) {
        float a = b11[0];
        for (int i = 0; i < 72; ++i) a += w11[i] * tc[i / 9];
        wfold[72] = a;
    }
}

// ---------------------------------------------------------------------------
// Final: att = sigmoid(conv 8->1 over NHWC gated), blend with im (NCHW fp32).
// ---------------------------------------------------------------------------
__global__ __launch_bounds__(256) void final_k(
    const unsigned short* __restrict__ gated, const float* __restrict__ wf,
    const float* __restrict__ im, const float* __restrict__ gamma,
    float* __restrict__ out)
{
    __shared__ __align__(16) unsigned short s_g[1156 * 8];
    __shared__ float s_w[80];

    int b = blockIdx.z;
    int x0 = blockIdx.x * 32, y0 = blockIdx.y * 32;
    int tid = threadIdx.x;
    int lane = tid & 63, wv = tid >> 6;
    bool interior = (x0 >= 1) && (x0 + 32 < W_) && (y0 >= 1) && (y0 + 32 < H_);

    if (tid < 73) s_w[tid] = wf[tid];

    const unsigned short* gb = gated + (size_t)b * HW_ * 8;
    if (interior) {
        const unsigned short* gb0 = gb + ((size_t)(y0 - 1) * W_ + (x0 - 1)) * 8;
        for (int base = wv * 64; base < 1156; base += 256) {
            int px = base + lane;
            if (px < 1156) {
                int y = px / 34;
                async_cp16(&s_g[(size_t)base * 8],
                           &gb0[(size_t)(px + y * 266) * 8]);
            }
        }
    } else {
        for (int e = tid; e < 1156; e += 256) {
            int y = e / 34, x = e - y * 34;
            int gy = y0 + y - 1, gx = x0 + x - 1;
            u16x8 v = {0, 0, 0, 0, 0, 0, 0, 0};
            if (gy >= 0 && gy < H_ && gx >= 0 && gx < W_)
                v = *(const u16x8*)&gb[((size_t)gy * W_ + gx) * 8];
            *(u16x8*)&s_g[e * 8] = v;
        }
    }
    __syncthreads();

    int qx = (tid & 15) * 2, qy = (tid >> 4) * 2;
    float f[4];
    float gm = *gamma;
#pragma unroll
    for (int p = 0; p < 4; ++p) {
        int ly = qy + (p >> 1), lx = qx + (p & 1);
        float acc = s_w[72];
#pragma unroll
        for (int t = 0; t < 9; ++t) {
            u16x8 n = *(const u16x8*)&s_g[((ly + t / 3) * 34 + lx + t % 3) * 8];
#pragma unroll
            for (int ci = 0; ci < 8; ++ci) acc += b2f(n[ci]) * s_w[t * 8 + ci];
        }
        f[p] = (1.f - gm) + gm * sigm(acc);
    }

    int px = x0 + qx, py = y0 + qy;
    if (px < W_) {
#pragma unroll
        for (int ch = 0; ch < 3; ++ch) {
            const float* imb = im + ((size_t)b * 3 + ch) * HW_;
            float* ob = out + ((size_t)b * 3 + ch) * HW_;
#pragma unroll
            for (int pr = 0; pr < 2; ++pr) {
                if (py + pr < H_) {
                    float2 iv = *(const float2*)&imb[(size_t)(py + pr) * W_ + px];
                    float2 ov;
                    ov.x = iv.x * f[pr * 2 + 0];
                    ov.y = iv.y * f[pr * 2 + 1];
                    *(float2*)&ob[(size_t)(py + pr) * W_ + px] = ov;
                }
            }
        }
    }
}

// ---------------------------------------------------------------------------

extern "C" void kernel_launch(void* const* d_in, const int* in_sizes, int n_in,
                              void* d_out, int out_size, void* d_ws,
                              size_t ws_size, hipStream_t stream)
{
    (void)in_sizes; (void)n_in; (void)out_size;

    const float* im  = (const float*)d_in[0];
    const float* w1  = (const float*)d_in[1];
    const float* b1  = (const float*)d_in[2];
    const float* w2  = (const float*)d_in[3];
    const float* b2  = (const float*)d_in[4];
    const float* w3  = (const float*)d_in[5];
    const float* b3  = (const float*)d_in[6];
    const float* w4  = (const float*)d_in[7];
    const float* b4  = (const float*)d_in[8];
    const float* w5  = (const float*)d_in[9];
    const float* b5  = (const float*)d_in[10];
    const float* wc5 = (const float*)d_in[11];
    const float* bc5 = (const float*)d_in[12];
    const float* wc10= (const float*)d_in[13];
    const float* bc10= (const float*)d_in[14];
    const float* wc15= (const float*)d_in[15];
    const float* bc15= (const float*)d_in[16];
    const float* wg  = (const float*)d_in[17];
    const float* bg  = (const float*)d_in[18];
    const float* wm  = (const float*)d_in[19];
    const float* bm  = (const float*)d_in[20];
    const float* bnw = (const float*)d_in[21];
    const float* bnb = (const float*)d_in[22];
    const float* w11 = (const float*)d_in[23];
    const float* b11 = (const float*)d_in[24];
    const float* gam = (const float*)d_in[25];
    float* out = (float*)d_out;

    // ---- workspace plan (chunked batch; deterministic in ws_size) ----------
    const size_t GATED_B = 46080000;
    const size_t PER_IMG = 1440000 + 2880000 + 5760000 + 57600 + 14400 + 6656;
    const size_t MISC    = 1048576;
    int c = 32;
    while (c > 1 && GATED_B + MISC + (size_t)c * PER_IMG + 2048 > ws_size)
        c >>= 1;

    char* p = (char*)d_ws;
    auto take = [&](size_t bytes) {
        char* r = p;
        p += (bytes + 255) & ~(size_t)255;
        return r;
    };
    unsigned short* GATED = (unsigned short*)take(GATED_B);
    unsigned short* A   = (unsigned short*)take((size_t)c * 1440000);
    unsigned short* Bb  = (unsigned short*)take((size_t)c * 2880000);
    unsigned short* C   = (unsigned short*)take((size_t)c * 5760000);
    unsigned short* P5  = (unsigned short*)take((size_t)c * 57600);
    unsigned short* P10 = (unsigned short*)take((size_t)c * 14400);
    unsigned short* P15 = (unsigned short*)take((size_t)c * 6656);
    float2* parts  = (float2*)take((size_t)NPART * 8 * sizeof(float2));
    float2* parts2 = (float2*)take(64 * 8 * sizeof(float2));
    float*  wfold  = (float*)take(512);
    unsigned short* WP = (unsigned short*)take(65536);

    unsigned short* PK2 = WP;            // conv2: 3 steps
    unsigned short* PK3 = WP + 2048;     // conv3: 5x2
    unsigned short* PK4 = WP + 8192;     // conv4: 9
    unsigned short* PK5 = WP + 13312;    // conv5: 5
    unsigned short* PKc = WP + 16384;    // convc composite: 9x2
    unsigned short* PKg = WP + 25600;    // gated: 9
    unsigned short* PK1 = WP + 30720;    // conv1: 3

    dim3 blk(256);

    pack_all_k<<<dim3(7), blk, 0, stream>>>(w1, w2, w3, w4, w5, wc5, wc10, wc15,
                                            wg, wm, WP);

    for (int b0 = 0; b0 < NBATCH; b0 += c) {
        dim3 g32(10, 10, c);   // TH=32 kernels
        dim3 g16(10, 19, c);   // TH=16 kernels
        const float* imc = im + (size_t)b0 * 3 * HW_;

        fused12_k<<<g32, blk, 0, stream>>>(imc, PK1, b1, PK2, b2, Bb);

        mfconv_k<16, 16, 32, 2, 0, 32><<<g32, blk, 0, stream>>>(
            Bb, PK3, b3, nullptr, C, 32, 0, nullptr, 0);
        mfconv_k<32, 32, 16, 1, 0, 16><<<g16, blk, 0, stream>>>(
            C, PK4, b4, nullptr, Bb, 16, 0, nullptr, 0);
        mfconv_k<16, 16, 8, 1, 0, 32><<<g32, blk, 0, stream>>>(
            Bb, PK5, b5, nullptr, A, 8, 0, nullptr, 0);

        int n5 = c * 3600, n10 = c * 900, n15 = c * 400;
        pool5_k<<<dim3((n5 + 255) / 256), blk, 0, stream>>>(A, P5, n5);
        poolrs_k<<<dim3((n10 + n15 + 255) / 256), blk, 0, stream>>>(P5, P10, P15,
                                                                    n10, n15);

        convc3_k<<<g32, blk, 0, stream>>>(A, P5, P10, P15, PKc, bc5, bc10, bc15, C);

        mfconv_k<24, 32, 16, 1, 2, 16><<<g16, blk, 0, stream>>>(
            C, PKg, bg, bm, GATED + (size_t)b0 * HW_ * 8, 8, 0, parts, b0);
    }

    reduce_parts_k<<<dim3(64), blk, 0, stream>>>(parts, parts2);
    stats_fold_k<<<dim3(1), blk, 0, stream>>>(parts2, bnw, bnb, w11, b11, wfold);
    final_k<<<dim3(10, 10, NBATCH), blk, 0, stream>>>(GATED, wfold, im, gam,
                                                      out);
}